// Round 14
// baseline (224.613 us; speedup 1.0000x reference)
//
#include <hip/hip_runtime.h>
#include <hip/hip_bf16.h>

// DA block (DANet) — Round 30: deduplicate k_pbm's QK work.
// R29 green at 202.6 µs (flash-no-max, k_pam2 deleted). k_pbm's 2 ch-half
// blocks computed IDENTICAL P tiles (QK+exp+LDS dup 2x, K loads dup 2x).
// Reshape: TI=32 rows x ALL 256 ch per block, grid (N/32,B)=256 blocks
// (same 1 blk/CU). Per-wave/iter: 22 MFMA vs 28 for same output; K traffic
// halved. Values bit-identical (same chains/order). Plus p_s block-rotation
// swizzle (write blk=(blk+i)&15, read same) vs 4.19M conflict cycles.
// All other kernels = R29-green.

#define B_ 2
#define C_ 256
#define N_ 4096
#define QK_ 32

#define TJ_ 128    // j per tile (8 waves x 16)
#define PPB_ 136   // p LDS pitch (bf16) = 272 B (16B-aligned rows)

typedef __hip_bfloat16 bf16;
typedef __attribute__((ext_vector_type(8))) short bf16x8f;   // MFMA A/B frag
typedef __attribute__((ext_vector_type(4))) float f32x4;     // MFMA C/D frag

union bf8pack { bf16 h[8]; int4 v; bf16x8f f; };
union bf4pack { bf16 h[4]; uint2 u; };

// ---- k_wcv: weights -> hi/lo bf16. wqk = [wq;wk] 64x256, wv 256x256 ----
__global__ __launch_bounds__(256) void k_wcv(
    const float* __restrict__ wq, const float* __restrict__ wk, const float* __restrict__ wv,
    bf16* __restrict__ wqkh, bf16* __restrict__ wqkl,
    bf16* __restrict__ wvh, bf16* __restrict__ wvl) {
  int idx = blockIdx.x * 256 + threadIdx.x;
  if (idx < 64 * C_) {
    int r = idx >> 8, c = idx & 255;
    float v = (r < 32) ? wq[r * C_ + c] : wk[(r - 32) * C_ + c];
    bf16 h = __float2bfloat16(v);
    wqkh[idx] = h; wqkl[idx] = __float2bfloat16(v - __bfloat162float(h));
  } else {
    int j = idx - 64 * C_;
    float v = wv[j];
    bf16 h = __float2bfloat16(v);
    wvh[j] = h; wvl[j] = __float2bfloat16(v - __bfloat162float(h));
  }
}

// ---- k_xt v2: x -> xT hi/lo [b][n][c] AND xc hi/lo [b][c][n] ----
__global__ __launch_bounds__(256) void k_xt(
    const float* __restrict__ x, bf16* __restrict__ xthi, bf16* __restrict__ xtlo,
    bf16* __restrict__ xchi, bf16* __restrict__ xclo) {
  int b = blockIdx.z;
  int c0 = blockIdx.y * 64;
  int n0 = blockIdx.x * 64;
  __shared__ float t[64 * 65];
  int tid = threadIdx.x;
  int col = tid & 63, rowq = tid >> 6;        // 4 rows per pass
#pragma unroll
  for (int k = 0; k < 16; k++) {
    int r = k * 4 + rowq;
    size_t src = ((size_t)b * C_ + c0 + r) * N_ + n0 + col;
    float v = x[src];
    t[r * 65 + col] = v;
    bf16 h = __float2bfloat16(v);            // same-layout bf16 hi/lo
    xchi[src] = h;
    xclo[src] = __float2bfloat16(v - __bfloat162float(h));
  }
  __syncthreads();
#pragma unroll
  for (int k = 0; k < 16; k++) {
    int nrow = k * 4 + rowq;
    float v = t[col * 65 + nrow];             // [c_local=col][n_local=nrow]
    bf16 h = __float2bfloat16(v);
    size_t o = ((size_t)b * N_ + n0 + nrow) * C_ + c0 + col;
    xthi[o] = h;
    xtlo[o] = __float2bfloat16(v - __bfloat162float(h));
  }
}

// ---- k_qkp: q/k proj via MFMA. A=wqk (rows o), B=xT (rows n), K=256 ----
__global__ __launch_bounds__(256) void k_qkp(
    const bf16* __restrict__ xthi, const bf16* __restrict__ xtlo,
    const bf16* __restrict__ wqkh, const bf16* __restrict__ wqkl,
    const float* __restrict__ bq, const float* __restrict__ bk,
    bf16* __restrict__ qhi, bf16* __restrict__ qlo,
    bf16* __restrict__ khi, bf16* __restrict__ klo) {
  int b = blockIdx.y;
  int tid = threadIdx.x;
  int lane = tid & 63, wave = tid >> 6;
  int n16 = lane & 15, quad = lane >> 4;
  int nb = blockIdx.x * 128 + wave * 32;

  f32x4 acc[4][2];                              // [ot][nt]
#pragma unroll
  for (int ot = 0; ot < 4; ot++)
#pragma unroll
    for (int nt = 0; nt < 2; nt++) acc[ot][nt] = (f32x4)(0.f);

#pragma unroll
  for (int kk = 0; kk < 8; kk++) {
    bf16x8f Ah[4], Al[4], Bh[2], Bl[2];
#pragma unroll
    for (int ot = 0; ot < 4; ot++) {
      size_t off = (size_t)(ot * 16 + n16) * C_ + kk * 32 + quad * 8;
      Ah[ot] = *(const bf16x8f*)(const void*)(wqkh + off);
      Al[ot] = *(const bf16x8f*)(const void*)(wqkl + off);
    }
#pragma unroll
    for (int nt = 0; nt < 2; nt++) {
      size_t off = ((size_t)b * N_ + nb + nt * 16 + n16) * C_ + kk * 32 + quad * 8;
      Bh[nt] = *(const bf16x8f*)(const void*)(xthi + off);
      Bl[nt] = *(const bf16x8f*)(const void*)(xtlo + off);
    }
#pragma unroll
    for (int ot = 0; ot < 4; ot++)
#pragma unroll
      for (int nt = 0; nt < 2; nt++) {
        acc[ot][nt] = __builtin_amdgcn_mfma_f32_16x16x32_bf16(Ah[ot], Bh[nt], acc[ot][nt], 0, 0, 0);
        acc[ot][nt] = __builtin_amdgcn_mfma_f32_16x16x32_bf16(Al[ot], Bh[nt], acc[ot][nt], 0, 0, 0);
        acc[ot][nt] = __builtin_amdgcn_mfma_f32_16x16x32_bf16(Ah[ot], Bl[nt], acc[ot][nt], 0, 0, 0);
      }
  }
#pragma unroll
  for (int ot = 0; ot < 4; ot++)
#pragma unroll
    for (int nt = 0; nt < 2; nt++) {
      int n = nb + nt * 16 + n16;
      int o0 = (ot & 1) * 16 + quad * 4;        // o within q or k (0..31)
      bf4pack ph, pl;
#pragma unroll
      for (int r = 0; r < 4; r++) {
        float v = acc[ot][nt][r] + (ot < 2 ? bq[o0 + r] : bk[o0 + r]);
        bf16 h = __float2bfloat16(v);
        ph.h[r] = h; pl.h[r] = __float2bfloat16(v - __bfloat162float(h));
      }
      size_t base = ((size_t)b * N_ + n) * QK_ + o0;
      if (ot < 2) { *(uint2*)(qhi + base) = ph.u; *(uint2*)(qlo + base) = pl.u; }
      else        { *(uint2*)(khi + base) = ph.u; *(uint2*)(klo + base) = pl.u; }
    }
}

// ---- k_vbf2: V proj via MFMA. A=wv (rows c), B=xT (rows n), K=256 ----
__global__ __launch_bounds__(256) void k_vbf2(
    const bf16* __restrict__ xthi, const bf16* __restrict__ xtlo,
    const bf16* __restrict__ wvh, const bf16* __restrict__ wvl,
    const float* __restrict__ bv, bf16* __restrict__ vbf) {
  int b = blockIdx.y;
  int n0 = blockIdx.x * 32;
  int tid = threadIdx.x;
  int lane = tid & 63, wave = tid >> 6;
  int n16 = lane & 15, quad = lane >> 4;
  int c0 = wave * 64;

  f32x4 acc[4][2];                              // [ct][nt]
#pragma unroll
  for (int ct = 0; ct < 4; ct++)
#pragma unroll
    for (int nt = 0; nt < 2; nt++) acc[ct][nt] = (f32x4)(0.f);

#pragma unroll
  for (int kk = 0; kk < 8; kk++) {
    bf16x8f Ah[4], Al[4], Bh[2], Bl[2];
#pragma unroll
    for (int ct = 0; ct < 4; ct++) {
      size_t off = (size_t)(c0 + ct * 16 + n16) * C_ + kk * 32 + quad * 8;
      Ah[ct] = *(const bf16x8f*)(const void*)(wvh + off);
      Al[ct] = *(const bf16x8f*)(const void*)(wvl + off);
    }
#pragma unroll
    for (int nt = 0; nt < 2; nt++) {
      size_t off = ((size_t)b * N_ + n0 + nt * 16 + n16) * C_ + kk * 32 + quad * 8;
      Bh[nt] = *(const bf16x8f*)(const void*)(xthi + off);
      Bl[nt] = *(const bf16x8f*)(const void*)(xtlo + off);
    }
#pragma unroll
    for (int ct = 0; ct < 4; ct++)
#pragma unroll
      for (int nt = 0; nt < 2; nt++) {
        acc[ct][nt] = __builtin_amdgcn_mfma_f32_16x16x32_bf16(Ah[ct], Bh[nt], acc[ct][nt], 0, 0, 0);
        acc[ct][nt] = __builtin_amdgcn_mfma_f32_16x16x32_bf16(Al[ct], Bh[nt], acc[ct][nt], 0, 0, 0);
        acc[ct][nt] = __builtin_amdgcn_mfma_f32_16x16x32_bf16(Ah[ct], Bl[nt], acc[ct][nt], 0, 0, 0);
      }
  }
#pragma unroll
  for (int ct = 0; ct < 4; ct++)
#pragma unroll
    for (int nt = 0; nt < 2; nt++) {
      int n = n0 + nt * 16 + n16;
      int cb = c0 + ct * 16 + quad * 4;
#pragma unroll
      for (int r = 0; r < 4; r++) {
        float v = acc[ct][nt][r] + bv[cb + r];
        vbf[((size_t)b * C_ + cb + r) * N_ + n] = __float2bfloat16(v);
      }
    }
}

// ---- k_pbm v14: TI=32 x 256ch, flash-no-max, swizzled p_s ----
// grid (N/32, B) = 256 blocks, 8 waves. Wave: 16-j slice for P; 32 ch for PV.
// P computed ONCE per i-tile (was 2x). Same values/order as v13.
__global__ __launch_bounds__(512) void k_pbm(
    const bf16* __restrict__ qhi, const bf16* __restrict__ qlo,
    const bf16* __restrict__ khi, const bf16* __restrict__ klo,
    const bf16* __restrict__ vbf,
    float* __restrict__ pamT) {
  int b = blockIdx.y;
  int i0 = blockIdx.x * 32;
  int tid = threadIdx.x;
  int lane = tid & 63, wave = tid >> 6;
  int n16 = lane & 15, quad = lane >> 4;

  __shared__ __align__(16) bf16 p_s[2][32 * PPB_];   // 17.4 KB double-buffered

  bf16x8f ahf[2], alf[2];
#pragma unroll
  for (int ih = 0; ih < 2; ih++) {
    size_t qoff = ((size_t)b * N_ + i0 + ih * 16 + n16) * QK_ + quad * 8;
    ahf[ih] = *(const bf16x8f*)(const void*)(qhi + qoff);
    alf[ih] = *(const bf16x8f*)(const void*)(qlo + qoff);
  }

  f32x4 acc[2][2];                               // [ih][cb]
  float l8[8];                                   // per-lane partial denominators
#pragma unroll
  for (int ih = 0; ih < 2; ih++)
#pragma unroll
    for (int cb = 0; cb < 2; cb++) acc[ih][cb] = (f32x4)(0.f);
#pragma unroll
  for (int k = 0; k < 8; k++) l8[k] = 0.f;

  const bf16* khb = khi + ((size_t)b * N_ + wave * 16 + n16) * QK_ + quad * 8;
  const bf16* klb = klo + ((size_t)b * N_ + wave * 16 + n16) * QK_ + quad * 8;
  const bf16* vb0 = vbf + ((size_t)b * C_ + wave * 32 + n16) * N_ + quad * 8;

  const int NJT = N_ / TJ_;                      // 32 iterations
  int wcol = wave * 16 + n16;                    // P write column
  int wblk = wcol >> 3, wrem = wcol & 7;

  // ---- prologue: produce P(0); load K(1), V(0) ----
  bf16x8f khf = *(const bf16x8f*)(const void*)khb;
  bf16x8f klf = *(const bf16x8f*)(const void*)klb;
  {
    bf16* pbuf = p_s[0];
#pragma unroll
    for (int ih = 0; ih < 2; ih++) {
      f32x4 t = (f32x4)(0.f);
      t = __builtin_amdgcn_mfma_f32_16x16x32_bf16(ahf[ih], khf, t, 0, 0, 0);
      t = __builtin_amdgcn_mfma_f32_16x16x32_bf16(alf[ih], khf, t, 0, 0, 0);
      t = __builtin_amdgcn_mfma_f32_16x16x32_bf16(ahf[ih], klf, t, 0, 0, 0);
#pragma unroll
      for (int r = 0; r < 4; r++) {
        int i = ih * 16 + quad * 4 + r;
        float p = __expf(t[r]);
        l8[ih * 4 + r] += p;
        pbuf[i * PPB_ + (((wblk + i) & 15) << 3) + wrem] = __float2bfloat16(p);
      }
    }
  }
  khf = *(const bf16x8f*)(const void*)(khb + (size_t)TJ_ * QK_);
  klf = *(const bf16x8f*)(const void*)(klb + (size_t)TJ_ * QK_);
  bf16x8f vcur[2][4];
#pragma unroll
  for (int cb = 0; cb < 2; cb++)
#pragma unroll
    for (int jhh = 0; jhh < 4; jhh++)
      vcur[cb][jhh] = *(const bf16x8f*)(const void*)(vb0 + (size_t)cb * 16 * N_ + jhh * 32);
  __syncthreads();                               // P(0) visible

  for (int jt = 0; jt < NJT; jt++) {
    // 1) QK(jt+1)
    f32x4 z[2];
    if (jt + 1 < NJT) {
#pragma unroll
      for (int ih = 0; ih < 2; ih++) {
        f32x4 t = (f32x4)(0.f);
        t = __builtin_amdgcn_mfma_f32_16x16x32_bf16(ahf[ih], khf, t, 0, 0, 0);
        t = __builtin_amdgcn_mfma_f32_16x16x32_bf16(alf[ih], khf, t, 0, 0, 0);
        t = __builtin_amdgcn_mfma_f32_16x16x32_bf16(ahf[ih], klf, t, 0, 0, 0);
        z[ih] = t;
      }
    }
    // 2) PV(jt): swizzled reads from p_s[jt&1]
    {
      const bf16* pbuf = p_s[jt & 1];
#pragma unroll
      for (int jhh = 0; jhh < 4; jhh++) {
        int jb = jhh * 4 + quad;                 // 16B block index (0..15)
        bf16x8f pa[2];
#pragma unroll
        for (int ih = 0; ih < 2; ih++) {
          int ir = ih * 16 + n16;
          pa[ih] = *(const bf16x8f*)(const void*)(pbuf + ir * PPB_ + (((jb + ir) & 15) << 3));
        }
#pragma unroll
        for (int ih = 0; ih < 2; ih++)
#pragma unroll
          for (int cb = 0; cb < 2; cb++)
            acc[ih][cb] = __builtin_amdgcn_mfma_f32_16x16x32_bf16(pa[ih], vcur[cb][jhh], acc[ih][cb], 0, 0, 0);
      }
    }
    // 3) exp -> write P(jt+1)
    if (jt + 1 < NJT) {
      bf16* pbuf = p_s[(jt + 1) & 1];
#pragma unroll
      for (int ih = 0; ih < 2; ih++)
#pragma unroll
        for (int r = 0; r < 4; r++) {
          int i = ih * 16 + quad * 4 + r;
          float p = __expf(z[ih][r]);
          l8[ih * 4 + r] += p;
          pbuf[i * PPB_ + (((wblk + i) & 15) << 3) + wrem] = __float2bfloat16(p);
        }
    }
    // 4) prefetch K(jt+2), V(jt+1)
    bf16x8f khn, kln, vnxt[2][4];
    if (jt + 2 < NJT) {
      size_t koff = (size_t)(jt + 2) * TJ_ * QK_;
      khn = *(const bf16x8f*)(const void*)(khb + koff);
      kln = *(const bf16x8f*)(const void*)(klb + koff);
    }
    if (jt + 1 < NJT) {
      int jb = (jt + 1) * TJ_;
#pragma unroll
      for (int cb = 0; cb < 2; cb++)
#pragma unroll
        for (int jhh = 0; jhh < 4; jhh++)
          vnxt[cb][jhh] = *(const bf16x8f*)(const void*)(vb0 + (size_t)cb * 16 * N_ + jb + jhh * 32);
    }
    // 5) barrier
    __syncthreads();
    khf = khn; klf = kln;
#pragma unroll
    for (int cb = 0; cb < 2; cb++)
#pragma unroll
      for (int jhh = 0; jhh < 4; jhh++) vcur[cb][jhh] = vnxt[cb][jhh];
  }

  // ---- epilogue: reduce l over 16 n16-lanes, then 8 waves; scale+store ----
#pragma unroll
  for (int d = 1; d < 16; d <<= 1)
#pragma unroll
    for (int k = 0; k < 8; k++)
      l8[k] += __shfl_xor(l8[k], d, 64);
  float* red = (float*)p_s;                      // 8*32 + 32 floats, aliases p_s
  float* linv = red + 8 * 32;
  if (n16 == 0) {
#pragma unroll
    for (int ih = 0; ih < 2; ih++)
#pragma unroll
      for (int r = 0; r < 4; r++)
        red[wave * 32 + ih * 16 + quad * 4 + r] = l8[ih * 4 + r];
  }
  __syncthreads();
  if (tid < 32) {
    float L = 0.f;
#pragma unroll
    for (int w = 0; w < 8; w++) L += red[w * 32 + tid];
    linv[tid] = 1.0f / L;
  }
  __syncthreads();
#pragma unroll
  for (int ih = 0; ih < 2; ih++)
#pragma unroll
    for (int cb = 0; cb < 2; cb++) {
      int c = wave * 32 + cb * 16 + n16;
#pragma unroll
      for (int r = 0; r < 4; r++) {
        int i = ih * 16 + quad * 4 + r;
        pamT[((size_t)b * N_ + i0 + i) * C_ + c] = acc[ih][cb][r] * linv[i];
      }
    }
}

// ---- k_ce2: CAM energy via MFMA hi/lo. e_p[kc][b][i][j] partials ----
__global__ __launch_bounds__(256) void k_ce2(
    const bf16* __restrict__ xchi, const bf16* __restrict__ xclo,
    float* __restrict__ eCp) {
  int b = blockIdx.z;
  int kc = blockIdx.y;
  int i0 = blockIdx.x * 32;
  int tid = threadIdx.x;
  int lane = tid & 63, wave = tid >> 6;
  int n16 = lane & 15, quad = lane >> 4;
  int j0 = wave * 64;

  f32x4 acc[2][4];                               // [it][jt]
#pragma unroll
  for (int it = 0; it < 2; it++)
#pragma unroll
    for (int jt = 0; jt < 4; jt++) acc[it][jt] = (f32x4)(0.f);

  size_t kb = (size_t)kc * 512;
#pragma unroll 2
  for (int kk = 0; kk < 16; kk++) {
    bf16x8f Ah[2], Al[2], Bh[4], Bl[4];
#pragma unroll
    for (int it = 0; it < 2; it++) {
      size_t off = ((size_t)b * C_ + i0 + it * 16 + n16) * N_ + kb + kk * 32 + quad * 8;
      Ah[it] = *(const bf16x8f*)(const void*)(xchi + off);
      Al[it] = *(const bf16x8f*)(const void*)(xclo + off);
    }
#pragma unroll
    for (int jt = 0; jt < 4; jt++) {
      size_t off = ((size_t)b * C_ + j0 + jt * 16 + n16) * N_ + kb + kk * 32 + quad * 8;
      Bh[jt] = *(const bf16x8f*)(const void*)(xchi + off);
      Bl[jt] = *(const bf16x8f*)(const void*)(xclo + off);
    }
#pragma unroll
    for (int it = 0; it < 2; it++)
#pragma unroll
      for (int jt = 0; jt < 4; jt++) {
        acc[it][jt] = __builtin_amdgcn_mfma_f32_16x16x32_bf16(Ah[it], Bh[jt], acc[it][jt], 0, 0, 0);
        acc[it][jt] = __builtin_amdgcn_mfma_f32_16x16x32_bf16(Al[it], Bh[jt], acc[it][jt], 0, 0, 0);
        acc[it][jt] = __builtin_amdgcn_mfma_f32_16x16x32_bf16(Ah[it], Bl[jt], acc[it][jt], 0, 0, 0);
      }
  }
  float* dst = eCp + ((size_t)kc * B_ + b) * C_ * C_;
#pragma unroll
  for (int it = 0; it < 2; it++)
#pragma unroll
    for (int jt = 0; jt < 4; jt++) {
      int i = i0 + it * 16 + quad * 4;
      int j = j0 + jt * 16 + n16;
#pragma unroll
      for (int r = 0; r < 4; r++)
        dst[(size_t)(i + r) * C_ + j] = acc[it][jt][r];
    }
}

// ---- k_cs v2: CAM softmax over -e; emit bf16 hi/lo ----
__global__ __launch_bounds__(256) void k_cs(
    const float* __restrict__ eCp, bf16* __restrict__ ahi, bf16* __restrict__ alo) {
  int row = blockIdx.x;
  int b = row >> 8, i = row & 255;
  int j = threadIdx.x;
  float e = 0.f;
#pragma unroll
  for (int kc = 0; kc < 8; kc++) e += eCp[(((size_t)kc * B_ + b) * C_ + i) * C_ + j];
  float ne = -e;
  __shared__ float buf[256];
  buf[j] = ne;
  __syncthreads();
  for (int st = 128; st >= 1; st >>= 1) {
    if (j < st) buf[j] = fmaxf(buf[j], buf[j + st]);
    __syncthreads();
  }
  float m = buf[0];
  __syncthreads();
  float p = __expf(ne - m);
  buf[j] = p;
  __syncthreads();
  for (int st = 128; st >= 1; st >>= 1) {
    if (j < st) buf[j] += buf[j + st];
    __syncthreads();
  }
  float v = p / buf[0];
  bf16 h = __float2bfloat16(v);
  ahi[(size_t)row * C_ + j] = h;
  alo[(size_t)row * C_ + j] = __float2bfloat16(v - __bfloat162float(h));
}

// ---- k_cam: cam[n][c] = sum_j xT[n][j]*attnC[c][j] (3-MFMA hi/lo),
//      fused: out = gp*pamT + gc*cam + 2x. grid (N/32, B), 512 thr ----
__global__ __launch_bounds__(512) void k_cam(
    const bf16* __restrict__ xthi, const bf16* __restrict__ xtlo,
    const bf16* __restrict__ ahi, const bf16* __restrict__ alo,
    const float* __restrict__ pamT, const float* __restrict__ x,
    const float* __restrict__ gpam, const float* __restrict__ gcam,
    float* __restrict__ out) {
  int b = blockIdx.y;
  int n0 = blockIdx.x * 32;
  int tid = threadIdx.x;
  int lane = tid & 63, wave = tid >> 6;
  int n16 = lane & 15, quad = lane >> 4;
  int c0 = wave * 32;

  f32x4 acc[2][2];                               // [nt][ct]
#pragma unroll
  for (int nt = 0; nt < 2; nt++)
#pragma unroll
    for (int ct = 0; ct < 2; ct++) acc[nt][ct] = (f32x4)(0.f);

#pragma unroll
  for (int kk = 0; kk < 8; kk++) {               // K = 256 = 8 x 32
    bf16x8f Ah[2], Al[2], Bh[2], Bl[2];
#pragma unroll
    for (int nt = 0; nt < 2; nt++) {
      size_t off = ((size_t)b * N_ + n0 + nt * 16 + n16) * C_ + kk * 32 + quad * 8;
      Ah[nt] = *(const bf16x8f*)(const void*)(xthi + off);
      Al[nt] = *(const bf16x8f*)(const void*)(xtlo + off);
    }
#pragma unroll
    for (int ct = 0; ct < 2; ct++) {
      size_t off = ((size_t)b * C_ + c0 + ct * 16 + n16) * C_ + kk * 32 + quad * 8;
      Bh[ct] = *(const bf16x8f*)(const void*)(ahi + off);
      Bl[ct] = *(const bf16x8f*)(const void*)(alo + off);
    }
#pragma unroll
    for (int nt = 0; nt < 2; nt++)
#pragma unroll
      for (int ct = 0; ct < 2; ct++) {
        acc[nt][ct] = __builtin_amdgcn_mfma_f32_16x16x32_bf16(Ah[nt], Bh[ct], acc[nt][ct], 0, 0, 0);
        acc[nt][ct] = __builtin_amdgcn_mfma_f32_16x16x32_bf16(Al[nt], Bh[ct], acc[nt][ct], 0, 0, 0);
        acc[nt][ct] = __builtin_amdgcn_mfma_f32_16x16x32_bf16(Ah[nt], Bl[ct], acc[nt][ct], 0, 0, 0);
      }
  }
  float gp = gpam[0], gc = gcam[0];
#pragma unroll
  for (int nt = 0; nt < 2; nt++)
#pragma unroll
    for (int ct = 0; ct < 2; ct++) {
      int c = c0 + ct * 16 + n16;
      int nb = n0 + nt * 16 + quad * 4;
      const float* xp = x + ((size_t)b * C_ + c) * N_ + nb;
      float4 x4 = *(const float4*)(const void*)xp;
      float4 o4;
      o4.x = gp * pamT[((size_t)b * N_ + nb + 0) * C_ + c] + gc * acc[nt][ct][0] + 2.0f * x4.x;
      o4.y = gp * pamT[((size_t)b * N_ + nb + 1) * C_ + c] + gc * acc[nt][ct][1] + 2.0f * x4.y;
      o4.z = gp * pamT[((size_t)b * N_ + nb + 2) * C_ + c] + gc * acc[nt][ct][2] + 2.0f * x4.z;
      o4.w = gp * pamT[((size_t)b * N_ + nb + 3) * C_ + c] + gc * acc[nt][ct][3] + 2.0f * x4.w;
      *(float4*)(out + ((size_t)b * C_ + c) * N_ + nb) = o4;
    }
}

extern "C" void kernel_launch(void* const* d_in, const int* in_sizes, int n_in,
                              void* d_out, int out_size, void* d_ws, size_t ws_size,
                              hipStream_t stream) {
  const float* x  = (const float*)d_in[0];
  const float* wq = (const float*)d_in[1];
  const float* bq = (const float*)d_in[2];
  const float* wk = (const float*)d_in[3];
  const float* bk = (const float*)d_in[4];
  const float* wv = (const float*)d_in[5];
  const float* bv = (const float*)d_in[6];
  const float* gp = (const float*)d_in[7];
  const float* gc = (const float*)d_in[8];
  float* out = (float*)d_out;

  float* ws = (float*)d_ws;
  size_t o = 0;
  float* pamT  = ws + o; o += (size_t)B_ * N_ * C_;     // 2097152
  float* mp    = ws + o; o += (size_t)2 * B_ * N_;      // 16384 (unused, layout kept)
  float* lp    = ws + o; o += (size_t)2 * B_ * N_;      // 16384 (unused, layout kept)
  float* eCp   = ws + o; o += (size_t)8 * B_ * C_ * C_; // 1048576
  bf16*  ahi   = (bf16*)(ws + o); o += (size_t)B_ * C_ * C_ / 2;   // 65536 fl
  bf16*  alo   = (bf16*)(ws + o); o += (size_t)B_ * C_ * C_ / 2;   // 65536 fl
  bf16*  vbf   = (bf16*)(ws + o); o += (size_t)B_ * N_ * C_ / 2;   // 1048576
  bf16*  qhi   = (bf16*)(ws + o); o += (size_t)B_ * N_ * QK_ / 2;  // 131072
  bf16*  qlo   = (bf16*)(ws + o); o += (size_t)B_ * N_ * QK_ / 2;  // 131072
  bf16*  khi   = (bf16*)(ws + o); o += (size_t)B_ * N_ * QK_ / 2;  // 131072
  bf16*  klo   = (bf16*)(ws + o); o += (size_t)B_ * N_ * QK_ / 2;  // 131072
  float* xtbuf = ws + o; o += (size_t)2 * B_ * N_ * QK_ * 4;       // 2097152 (xT hi/lo)
  bf16* xthi = (bf16*)xtbuf;
  bf16* xtlo = (bf16*)(xtbuf + (size_t)B_ * N_ * C_ / 2);
  // weight hi/lo buffers alias eCp (dead until k_ce2; k_qkp/k_vbf2 run first)
  bf16* wqkh = (bf16*)eCp;
  bf16* wqkl = wqkh + (size_t)64 * C_;
  bf16* wvh  = wqkl + (size_t)64 * C_;
  bf16* wvl  = wvh + (size_t)C_ * C_;
  // x [b][c][n] hi/lo alias pamT (dead until k_pbm; k_ce2/k_cs run before)
  bf16* xchi = (bf16*)pamT;
  bf16* xclo = xchi + (size_t)B_ * C_ * N_;     // 2x 1M floats = exact fit
  (void)mp; (void)lp;
  // total ~6.8 M floats = 27.4 MB (unchanged)

  k_wcv<<<dim3((64 * C_ + C_ * C_) / 256), dim3(256), 0, stream>>>(wq, wk, wv, wqkh, wqkl, wvh, wvl);
  k_xt<<<dim3(N_ / 64, C_ / 64, B_), dim3(256), 0, stream>>>(x, xthi, xtlo, xchi, xclo);
  k_qkp<<<dim3(N_ / 128, B_), dim3(256), 0, stream>>>(xthi, xtlo, wqkh, wqkl, bq, bk, qhi, qlo, khi, klo);
  k_vbf2<<<dim3(N_ / 32, B_), dim3(256), 0, stream>>>(xthi, xtlo, wvh, wvl, bv, vbf);
  k_ce2<<<dim3(C_ / 32, 8, B_), dim3(256), 0, stream>>>(xchi, xclo, eCp);
  k_cs<<<dim3(B_ * C_), dim3(256), 0, stream>>>(eCp, ahi, alo);
  k_pbm<<<dim3(N_ / 32, B_), dim3(512), 0, stream>>>(qhi, qlo, khi, klo, vbf, pamT);
  k_cam<<<dim3(N_ / 32, B_), dim3(512), 0, stream>>>(xthi, xtlo, ahi, alo, pamT, x, gp, gc, out);
}

// Round 15
// 211.258 us; speedup vs baseline: 1.0632x; 1.0632x over previous
//
#include <hip/hip_runtime.h>
#include <hip/hip_bf16.h>

// DA block (DANet) — Round 31: j-half split k_pbm (TI=64, all 256 ch).
// R30 post-mortem: TI=32 halved V amortization (V traffic 2x) -> regression.
// Law: time ∝ per-CU load volume. j-split is the only clean split: per block
// K-half 256KB + V-half 1MB = 1.27MB (R29: 1.5MB) AND no QK duplication.
// Partial O_unnorm + partial l merged by unsafeAtomicAdd (2 commutative fp32
// adds -> deterministic); pamT/lsum zeroed in k_cs; 1/l folded into k_cam.
// Keeps R30's p_s rotation swizzle (conflicts 4.19M->1.05M).
// All other kernels = R29-green.

#define B_ 2
#define C_ 256
#define N_ 4096
#define QK_ 32

#define TJ_ 128    // j per tile (8 waves x 16)
#define PPB_ 136   // p LDS pitch (bf16) = 272 B (16B-aligned rows)

typedef __hip_bfloat16 bf16;
typedef __attribute__((ext_vector_type(8))) short bf16x8f;   // MFMA A/B frag
typedef __attribute__((ext_vector_type(4))) float f32x4;     // MFMA C/D frag

union bf8pack { bf16 h[8]; int4 v; bf16x8f f; };
union bf4pack { bf16 h[4]; uint2 u; };

// ---- k_wcv: weights -> hi/lo bf16. wqk = [wq;wk] 64x256, wv 256x256 ----
__global__ __launch_bounds__(256) void k_wcv(
    const float* __restrict__ wq, const float* __restrict__ wk, const float* __restrict__ wv,
    bf16* __restrict__ wqkh, bf16* __restrict__ wqkl,
    bf16* __restrict__ wvh, bf16* __restrict__ wvl) {
  int idx = blockIdx.x * 256 + threadIdx.x;
  if (idx < 64 * C_) {
    int r = idx >> 8, c = idx & 255;
    float v = (r < 32) ? wq[r * C_ + c] : wk[(r - 32) * C_ + c];
    bf16 h = __float2bfloat16(v);
    wqkh[idx] = h; wqkl[idx] = __float2bfloat16(v - __bfloat162float(h));
  } else {
    int j = idx - 64 * C_;
    float v = wv[j];
    bf16 h = __float2bfloat16(v);
    wvh[j] = h; wvl[j] = __float2bfloat16(v - __bfloat162float(h));
  }
}

// ---- k_xt v2: x -> xT hi/lo [b][n][c] AND xc hi/lo [b][c][n] ----
__global__ __launch_bounds__(256) void k_xt(
    const float* __restrict__ x, bf16* __restrict__ xthi, bf16* __restrict__ xtlo,
    bf16* __restrict__ xchi, bf16* __restrict__ xclo) {
  int b = blockIdx.z;
  int c0 = blockIdx.y * 64;
  int n0 = blockIdx.x * 64;
  __shared__ float t[64 * 65];
  int tid = threadIdx.x;
  int col = tid & 63, rowq = tid >> 6;        // 4 rows per pass
#pragma unroll
  for (int k = 0; k < 16; k++) {
    int r = k * 4 + rowq;
    size_t src = ((size_t)b * C_ + c0 + r) * N_ + n0 + col;
    float v = x[src];
    t[r * 65 + col] = v;
    bf16 h = __float2bfloat16(v);            // same-layout bf16 hi/lo
    xchi[src] = h;
    xclo[src] = __float2bfloat16(v - __bfloat162float(h));
  }
  __syncthreads();
#pragma unroll
  for (int k = 0; k < 16; k++) {
    int nrow = k * 4 + rowq;
    float v = t[col * 65 + nrow];             // [c_local=col][n_local=nrow]
    bf16 h = __float2bfloat16(v);
    size_t o = ((size_t)b * N_ + n0 + nrow) * C_ + c0 + col;
    xthi[o] = h;
    xtlo[o] = __float2bfloat16(v - __bfloat162float(h));
  }
}

// ---- k_qkp: q/k proj via MFMA. A=wqk (rows o), B=xT (rows n), K=256 ----
__global__ __launch_bounds__(256) void k_qkp(
    const bf16* __restrict__ xthi, const bf16* __restrict__ xtlo,
    const bf16* __restrict__ wqkh, const bf16* __restrict__ wqkl,
    const float* __restrict__ bq, const float* __restrict__ bk,
    bf16* __restrict__ qhi, bf16* __restrict__ qlo,
    bf16* __restrict__ khi, bf16* __restrict__ klo) {
  int b = blockIdx.y;
  int tid = threadIdx.x;
  int lane = tid & 63, wave = tid >> 6;
  int n16 = lane & 15, quad = lane >> 4;
  int nb = blockIdx.x * 128 + wave * 32;

  f32x4 acc[4][2];                              // [ot][nt]
#pragma unroll
  for (int ot = 0; ot < 4; ot++)
#pragma unroll
    for (int nt = 0; nt < 2; nt++) acc[ot][nt] = (f32x4)(0.f);

#pragma unroll
  for (int kk = 0; kk < 8; kk++) {
    bf16x8f Ah[4], Al[4], Bh[2], Bl[2];
#pragma unroll
    for (int ot = 0; ot < 4; ot++) {
      size_t off = (size_t)(ot * 16 + n16) * C_ + kk * 32 + quad * 8;
      Ah[ot] = *(const bf16x8f*)(const void*)(wqkh + off);
      Al[ot] = *(const bf16x8f*)(const void*)(wqkl + off);
    }
#pragma unroll
    for (int nt = 0; nt < 2; nt++) {
      size_t off = ((size_t)b * N_ + nb + nt * 16 + n16) * C_ + kk * 32 + quad * 8;
      Bh[nt] = *(const bf16x8f*)(const void*)(xthi + off);
      Bl[nt] = *(const bf16x8f*)(const void*)(xtlo + off);
    }
#pragma unroll
    for (int ot = 0; ot < 4; ot++)
#pragma unroll
      for (int nt = 0; nt < 2; nt++) {
        acc[ot][nt] = __builtin_amdgcn_mfma_f32_16x16x32_bf16(Ah[ot], Bh[nt], acc[ot][nt], 0, 0, 0);
        acc[ot][nt] = __builtin_amdgcn_mfma_f32_16x16x32_bf16(Al[ot], Bh[nt], acc[ot][nt], 0, 0, 0);
        acc[ot][nt] = __builtin_amdgcn_mfma_f32_16x16x32_bf16(Ah[ot], Bl[nt], acc[ot][nt], 0, 0, 0);
      }
  }
#pragma unroll
  for (int ot = 0; ot < 4; ot++)
#pragma unroll
    for (int nt = 0; nt < 2; nt++) {
      int n = nb + nt * 16 + n16;
      int o0 = (ot & 1) * 16 + quad * 4;        // o within q or k (0..31)
      bf4pack ph, pl;
#pragma unroll
      for (int r = 0; r < 4; r++) {
        float v = acc[ot][nt][r] + (ot < 2 ? bq[o0 + r] : bk[o0 + r]);
        bf16 h = __float2bfloat16(v);
        ph.h[r] = h; pl.h[r] = __float2bfloat16(v - __bfloat162float(h));
      }
      size_t base = ((size_t)b * N_ + n) * QK_ + o0;
      if (ot < 2) { *(uint2*)(qhi + base) = ph.u; *(uint2*)(qlo + base) = pl.u; }
      else        { *(uint2*)(khi + base) = ph.u; *(uint2*)(klo + base) = pl.u; }
    }
}

// ---- k_vbf2: V proj via MFMA. A=wv (rows c), B=xT (rows n), K=256 ----
__global__ __launch_bounds__(256) void k_vbf2(
    const bf16* __restrict__ xthi, const bf16* __restrict__ xtlo,
    const bf16* __restrict__ wvh, const bf16* __restrict__ wvl,
    const float* __restrict__ bv, bf16* __restrict__ vbf) {
  int b = blockIdx.y;
  int n0 = blockIdx.x * 32;
  int tid = threadIdx.x;
  int lane = tid & 63, wave = tid >> 6;
  int n16 = lane & 15, quad = lane >> 4;
  int c0 = wave * 64;

  f32x4 acc[4][2];                              // [ct][nt]
#pragma unroll
  for (int ct = 0; ct < 4; ct++)
#pragma unroll
    for (int nt = 0; nt < 2; nt++) acc[ct][nt] = (f32x4)(0.f);

#pragma unroll
  for (int kk = 0; kk < 8; kk++) {
    bf16x8f Ah[4], Al[4], Bh[2], Bl[2];
#pragma unroll
    for (int ct = 0; ct < 4; ct++) {
      size_t off = (size_t)(c0 + ct * 16 + n16) * C_ + kk * 32 + quad * 8;
      Ah[ct] = *(const bf16x8f*)(const void*)(wvh + off);
      Al[ct] = *(const bf16x8f*)(const void*)(wvl + off);
    }
#pragma unroll
    for (int nt = 0; nt < 2; nt++) {
      size_t off = ((size_t)b * N_ + n0 + nt * 16 + n16) * C_ + kk * 32 + quad * 8;
      Bh[nt] = *(const bf16x8f*)(const void*)(xthi + off);
      Bl[nt] = *(const bf16x8f*)(const void*)(xtlo + off);
    }
#pragma unroll
    for (int ct = 0; ct < 4; ct++)
#pragma unroll
      for (int nt = 0; nt < 2; nt++) {
        acc[ct][nt] = __builtin_amdgcn_mfma_f32_16x16x32_bf16(Ah[ct], Bh[nt], acc[ct][nt], 0, 0, 0);
        acc[ct][nt] = __builtin_amdgcn_mfma_f32_16x16x32_bf16(Al[ct], Bh[nt], acc[ct][nt], 0, 0, 0);
        acc[ct][nt] = __builtin_amdgcn_mfma_f32_16x16x32_bf16(Ah[ct], Bl[nt], acc[ct][nt], 0, 0, 0);
      }
  }
#pragma unroll
  for (int ct = 0; ct < 4; ct++)
#pragma unroll
    for (int nt = 0; nt < 2; nt++) {
      int n = n0 + nt * 16 + n16;
      int cb = c0 + ct * 16 + quad * 4;
#pragma unroll
      for (int r = 0; r < 4; r++) {
        float v = acc[ct][nt][r] + bv[cb + r];
        vbf[((size_t)b * C_ + cb + r) * N_ + n] = __float2bfloat16(v);
      }
    }
}

// ---- k_pbm v15: TI=64 x 256ch x j-HALF; flash-no-max; atomic O/l merge ----
// grid (N/64, 2, B), 512 thr. Wave: 16-j slice for P (64 rows, 12 QK MFMA);
// 32 ch for PV (32 MFMA). p_s rotation swizzle. Outputs UNNORMALIZED;
// k_cam divides by lsum. pamT/lsum zeroed by k_cs (runs just before).
__global__ __launch_bounds__(512) void k_pbm(
    const bf16* __restrict__ qhi, const bf16* __restrict__ qlo,
    const bf16* __restrict__ khi, const bf16* __restrict__ klo,
    const bf16* __restrict__ vbf,
    float* __restrict__ pamT, float* __restrict__ lsum) {
  int b = blockIdx.z;
  int jh = blockIdx.y;
  size_t j0 = (size_t)jh * (N_ / 2);
  int i0 = blockIdx.x * 64;
  int tid = threadIdx.x;
  int lane = tid & 63, wave = tid >> 6;
  int n16 = lane & 15, quad = lane >> 4;

  __shared__ __align__(16) bf16 p_s[2][64 * PPB_];   // 34.8 KB double-buffered

  bf16x8f ahf[4], alf[4];
#pragma unroll
  for (int ih = 0; ih < 4; ih++) {
    size_t qoff = ((size_t)b * N_ + i0 + ih * 16 + n16) * QK_ + quad * 8;
    ahf[ih] = *(const bf16x8f*)(const void*)(qhi + qoff);
    alf[ih] = *(const bf16x8f*)(const void*)(qlo + qoff);
  }

  f32x4 acc[4][2];                               // [ih][cb]
  float l16[16];
#pragma unroll
  for (int ih = 0; ih < 4; ih++)
#pragma unroll
    for (int cb = 0; cb < 2; cb++) acc[ih][cb] = (f32x4)(0.f);
#pragma unroll
  for (int k = 0; k < 16; k++) l16[k] = 0.f;

  const bf16* khb = khi + ((size_t)b * N_ + j0 + wave * 16 + n16) * QK_ + quad * 8;
  const bf16* klb = klo + ((size_t)b * N_ + j0 + wave * 16 + n16) * QK_ + quad * 8;
  const bf16* vb0 = vbf + ((size_t)b * C_ + wave * 32 + n16) * N_ + j0 + quad * 8;

  const int NJT = (N_ / 2) / TJ_;                // 16 iterations
  int wcol = wave * 16 + n16;
  int wblk = wcol >> 3, wrem = wcol & 7;

  // ---- prologue: produce P(0); load K(1), V(0) ----
  bf16x8f khf = *(const bf16x8f*)(const void*)khb;
  bf16x8f klf = *(const bf16x8f*)(const void*)klb;
  {
    bf16* pbuf = p_s[0];
#pragma unroll
    for (int ih = 0; ih < 4; ih++) {
      f32x4 t = (f32x4)(0.f);
      t = __builtin_amdgcn_mfma_f32_16x16x32_bf16(ahf[ih], khf, t, 0, 0, 0);
      t = __builtin_amdgcn_mfma_f32_16x16x32_bf16(alf[ih], khf, t, 0, 0, 0);
      t = __builtin_amdgcn_mfma_f32_16x16x32_bf16(ahf[ih], klf, t, 0, 0, 0);
#pragma unroll
      for (int r = 0; r < 4; r++) {
        int i = ih * 16 + quad * 4 + r;
        float p = __expf(t[r]);
        l16[ih * 4 + r] += p;
        pbuf[i * PPB_ + (((wblk + i) & 15) << 3) + wrem] = __float2bfloat16(p);
      }
    }
  }
  khf = *(const bf16x8f*)(const void*)(khb + (size_t)TJ_ * QK_);
  klf = *(const bf16x8f*)(const void*)(klb + (size_t)TJ_ * QK_);
  bf16x8f vcur[2][4];
#pragma unroll
  for (int cb = 0; cb < 2; cb++)
#pragma unroll
    for (int jhh = 0; jhh < 4; jhh++)
      vcur[cb][jhh] = *(const bf16x8f*)(const void*)(vb0 + (size_t)cb * 16 * N_ + jhh * 32);
  __syncthreads();                               // P(0) visible

  for (int jt = 0; jt < NJT; jt++) {
    // 1) QK(jt+1)
    f32x4 z[4];
    if (jt + 1 < NJT) {
#pragma unroll
      for (int ih = 0; ih < 4; ih++) {
        f32x4 t = (f32x4)(0.f);
        t = __builtin_amdgcn_mfma_f32_16x16x32_bf16(ahf[ih], khf, t, 0, 0, 0);
        t = __builtin_amdgcn_mfma_f32_16x16x32_bf16(alf[ih], khf, t, 0, 0, 0);
        t = __builtin_amdgcn_mfma_f32_16x16x32_bf16(ahf[ih], klf, t, 0, 0, 0);
        z[ih] = t;
      }
    }
    // 2) PV(jt): swizzled reads
    {
      const bf16* pbuf = p_s[jt & 1];
#pragma unroll
      for (int jhh = 0; jhh < 4; jhh++) {
        int jb = jhh * 4 + quad;                 // 16B block index (0..15)
        bf16x8f pa[4];
#pragma unroll
        for (int ih = 0; ih < 4; ih++) {
          int ir = ih * 16 + n16;
          pa[ih] = *(const bf16x8f*)(const void*)(pbuf + ir * PPB_ + (((jb + ir) & 15) << 3));
        }
#pragma unroll
        for (int ih = 0; ih < 4; ih++)
#pragma unroll
          for (int cb = 0; cb < 2; cb++)
            acc[ih][cb] = __builtin_amdgcn_mfma_f32_16x16x32_bf16(pa[ih], vcur[cb][jhh], acc[ih][cb], 0, 0, 0);
      }
    }
    // 3) exp -> write P(jt+1)
    if (jt + 1 < NJT) {
      bf16* pbuf = p_s[(jt + 1) & 1];
#pragma unroll
      for (int ih = 0; ih < 4; ih++)
#pragma unroll
        for (int r = 0; r < 4; r++) {
          int i = ih * 16 + quad * 4 + r;
          float p = __expf(z[ih][r]);
          l16[ih * 4 + r] += p;
          pbuf[i * PPB_ + (((wblk + i) & 15) << 3) + wrem] = __float2bfloat16(p);
        }
    }
    // 4) prefetch K(jt+2), V(jt+1)
    bf16x8f khn, kln, vnxt[2][4];
    if (jt + 2 < NJT) {
      size_t koff = (size_t)(jt + 2) * TJ_ * QK_;
      khn = *(const bf16x8f*)(const void*)(khb + koff);
      kln = *(const bf16x8f*)(const void*)(klb + koff);
    }
    if (jt + 1 < NJT) {
      int jb = (jt + 1) * TJ_;
#pragma unroll
      for (int cb = 0; cb < 2; cb++)
#pragma unroll
        for (int jhh = 0; jhh < 4; jhh++)
          vnxt[cb][jhh] = *(const bf16x8f*)(const void*)(vb0 + (size_t)cb * 16 * N_ + jb + jhh * 32);
    }
    // 5) barrier
    __syncthreads();
    khf = khn; klf = kln;
#pragma unroll
    for (int cb = 0; cb < 2; cb++)
#pragma unroll
      for (int jhh = 0; jhh < 4; jhh++) vcur[cb][jhh] = vnxt[cb][jhh];
  }

  // ---- epilogue: partial l -> atomic; partial O_unnorm -> atomic ----
#pragma unroll
  for (int d = 1; d < 16; d <<= 1)
#pragma unroll
    for (int k = 0; k < 16; k++)
      l16[k] += __shfl_xor(l16[k], d, 64);
  float* red = (float*)p_s;                      // 8*64 floats, aliases p_s
  if (n16 == 0) {
#pragma unroll
    for (int ih = 0; ih < 4; ih++)
#pragma unroll
      for (int r = 0; r < 4; r++)
        red[wave * 64 + ih * 16 + quad * 4 + r] = l16[ih * 4 + r];
  }
  __syncthreads();
  if (tid < 64) {
    float L = 0.f;
#pragma unroll
    for (int w = 0; w < 8; w++) L += red[w * 64 + tid];
    unsafeAtomicAdd(&lsum[(size_t)b * N_ + i0 + tid], L);
  }
#pragma unroll
  for (int ih = 0; ih < 4; ih++)
#pragma unroll
    for (int cb = 0; cb < 2; cb++) {
      int c = wave * 32 + cb * 16 + n16;
#pragma unroll
      for (int r = 0; r < 4; r++) {
        int i = ih * 16 + quad * 4 + r;
        unsafeAtomicAdd(&pamT[((size_t)b * N_ + i0 + i) * C_ + c], acc[ih][cb][r]);
      }
    }
}

// ---- k_ce2: CAM energy via MFMA hi/lo. e_p[kc][b][i][j] partials ----
__global__ __launch_bounds__(256) void k_ce2(
    const bf16* __restrict__ xchi, const bf16* __restrict__ xclo,
    float* __restrict__ eCp) {
  int b = blockIdx.z;
  int kc = blockIdx.y;
  int i0 = blockIdx.x * 32;
  int tid = threadIdx.x;
  int lane = tid & 63, wave = tid >> 6;
  int n16 = lane & 15, quad = lane >> 4;
  int j0 = wave * 64;

  f32x4 acc[2][4];                               // [it][jt]
#pragma unroll
  for (int it = 0; it < 2; it++)
#pragma unroll
    for (int jt = 0; jt < 4; jt++) acc[it][jt] = (f32x4)(0.f);

  size_t kb = (size_t)kc * 512;
#pragma unroll 2
  for (int kk = 0; kk < 16; kk++) {
    bf16x8f Ah[2], Al[2], Bh[4], Bl[4];
#pragma unroll
    for (int it = 0; it < 2; it++) {
      size_t off = ((size_t)b * C_ + i0 + it * 16 + n16) * N_ + kb + kk * 32 + quad * 8;
      Ah[it] = *(const bf16x8f*)(const void*)(xchi + off);
      Al[it] = *(const bf16x8f*)(const void*)(xclo + off);
    }
#pragma unroll
    for (int jt = 0; jt < 4; jt++) {
      size_t off = ((size_t)b * C_ + j0 + jt * 16 + n16) * N_ + kb + kk * 32 + quad * 8;
      Bh[jt] = *(const bf16x8f*)(const void*)(xchi + off);
      Bl[jt] = *(const bf16x8f*)(const void*)(xclo + off);
    }
#pragma unroll
    for (int it = 0; it < 2; it++)
#pragma unroll
      for (int jt = 0; jt < 4; jt++) {
        acc[it][jt] = __builtin_amdgcn_mfma_f32_16x16x32_bf16(Ah[it], Bh[jt], acc[it][jt], 0, 0, 0);
        acc[it][jt] = __builtin_amdgcn_mfma_f32_16x16x32_bf16(Al[it], Bh[jt], acc[it][jt], 0, 0, 0);
        acc[it][jt] = __builtin_amdgcn_mfma_f32_16x16x32_bf16(Ah[it], Bl[jt], acc[it][jt], 0, 0, 0);
      }
  }
  float* dst = eCp + ((size_t)kc * B_ + b) * C_ * C_;
#pragma unroll
  for (int it = 0; it < 2; it++)
#pragma unroll
    for (int jt = 0; jt < 4; jt++) {
      int i = i0 + it * 16 + quad * 4;
      int j = j0 + jt * 16 + n16;
#pragma unroll
      for (int r = 0; r < 4; r++)
        dst[(size_t)(i + r) * C_ + j] = acc[it][jt][r];
    }
}

// ---- k_cs v3: CAM softmax over -e; emit bf16 hi/lo; zero pamT/lsum ----
__global__ __launch_bounds__(256) void k_cs(
    const float* __restrict__ eCp, bf16* __restrict__ ahi, bf16* __restrict__ alo,
    float* __restrict__ pamZ, float* __restrict__ lsum) {
  int row = blockIdx.x;
  int b = row >> 8, i = row & 255;
  int j = threadIdx.x;
  // zero pamT (2M floats: 512 blk x 256 thr x 16) and lsum (8192)
  {
    int t = row * 256 + j;
    float4* pz = (float4*)(pamZ + (size_t)t * 16);
    float4 z4 = make_float4(0.f, 0.f, 0.f, 0.f);
    pz[0] = z4; pz[1] = z4; pz[2] = z4; pz[3] = z4;
    if (t < B_ * N_) lsum[t] = 0.f;
  }
  float e = 0.f;
#pragma unroll
  for (int kc = 0; kc < 8; kc++) e += eCp[(((size_t)kc * B_ + b) * C_ + i) * C_ + j];
  float ne = -e;
  __shared__ float buf[256];
  buf[j] = ne;
  __syncthreads();
  for (int st = 128; st >= 1; st >>= 1) {
    if (j < st) buf[j] = fmaxf(buf[j], buf[j + st]);
    __syncthreads();
  }
  float m = buf[0];
  __syncthreads();
  float p = __expf(ne - m);
  buf[j] = p;
  __syncthreads();
  for (int st = 128; st >= 1; st >>= 1) {
    if (j < st) buf[j] += buf[j + st];
    __syncthreads();
  }
  float v = p / buf[0];
  bf16 h = __float2bfloat16(v);
  ahi[(size_t)row * C_ + j] = h;
  alo[(size_t)row * C_ + j] = __float2bfloat16(v - __bfloat162float(h));
}

// ---- k_cam v4: fused out = gp*O_unnorm/l + gc*cam + 2x ----
__global__ __launch_bounds__(512) void k_cam(
    const bf16* __restrict__ xthi, const bf16* __restrict__ xtlo,
    const bf16* __restrict__ ahi, const bf16* __restrict__ alo,
    const float* __restrict__ pamT, const float* __restrict__ lsum,
    const float* __restrict__ x,
    const float* __restrict__ gpam, const float* __restrict__ gcam,
    float* __restrict__ out) {
  int b = blockIdx.y;
  int n0 = blockIdx.x * 32;
  int tid = threadIdx.x;
  int lane = tid & 63, wave = tid >> 6;
  int n16 = lane & 15, quad = lane >> 4;
  int c0 = wave * 32;

  f32x4 acc[2][2];                               // [nt][ct]
#pragma unroll
  for (int nt = 0; nt < 2; nt++)
#pragma unroll
    for (int ct = 0; ct < 2; ct++) acc[nt][ct] = (f32x4)(0.f);

#pragma unroll
  for (int kk = 0; kk < 8; kk++) {               // K = 256 = 8 x 32
    bf16x8f Ah[2], Al[2], Bh[2], Bl[2];
#pragma unroll
    for (int nt = 0; nt < 2; nt++) {
      size_t off = ((size_t)b * N_ + n0 + nt * 16 + n16) * C_ + kk * 32 + quad * 8;
      Ah[nt] = *(const bf16x8f*)(const void*)(xthi + off);
      Al[nt] = *(const bf16x8f*)(const void*)(xtlo + off);
    }
#pragma unroll
    for (int ct = 0; ct < 2; ct++) {
      size_t off = ((size_t)b * C_ + c0 + ct * 16 + n16) * C_ + kk * 32 + quad * 8;
      Bh[ct] = *(const bf16x8f*)(const void*)(ahi + off);
      Bl[ct] = *(const bf16x8f*)(const void*)(alo + off);
    }
#pragma unroll
    for (int nt = 0; nt < 2; nt++)
#pragma unroll
      for (int ct = 0; ct < 2; ct++) {
        acc[nt][ct] = __builtin_amdgcn_mfma_f32_16x16x32_bf16(Ah[nt], Bh[ct], acc[nt][ct], 0, 0, 0);
        acc[nt][ct] = __builtin_amdgcn_mfma_f32_16x16x32_bf16(Al[nt], Bh[ct], acc[nt][ct], 0, 0, 0);
        acc[nt][ct] = __builtin_amdgcn_mfma_f32_16x16x32_bf16(Ah[nt], Bl[ct], acc[nt][ct], 0, 0, 0);
      }
  }
  float gp = gpam[0], gc = gcam[0];
  float linv[2][4];
#pragma unroll
  for (int nt = 0; nt < 2; nt++) {
    int nb = n0 + nt * 16 + quad * 4;
#pragma unroll
    for (int r = 0; r < 4; r++)
      linv[nt][r] = 1.0f / lsum[(size_t)b * N_ + nb + r];
  }
#pragma unroll
  for (int nt = 0; nt < 2; nt++)
#pragma unroll
    for (int ct = 0; ct < 2; ct++) {
      int c = c0 + ct * 16 + n16;
      int nb = n0 + nt * 16 + quad * 4;
      const float* xp = x + ((size_t)b * C_ + c) * N_ + nb;
      float4 x4 = *(const float4*)(const void*)xp;
      float4 o4;
      o4.x = gp * pamT[((size_t)b * N_ + nb + 0) * C_ + c] * linv[nt][0] + gc * acc[nt][ct][0] + 2.0f * x4.x;
      o4.y = gp * pamT[((size_t)b * N_ + nb + 1) * C_ + c] * linv[nt][1] + gc * acc[nt][ct][1] + 2.0f * x4.y;
      o4.z = gp * pamT[((size_t)b * N_ + nb + 2) * C_ + c] * linv[nt][2] + gc * acc[nt][ct][2] + 2.0f * x4.z;
      o4.w = gp * pamT[((size_t)b * N_ + nb + 3) * C_ + c] * linv[nt][3] + gc * acc[nt][ct][3] + 2.0f * x4.w;
      *(float4*)(out + ((size_t)b * C_ + c) * N_ + nb) = o4;
    }
}

extern "C" void kernel_launch(void* const* d_in, const int* in_sizes, int n_in,
                              void* d_out, int out_size, void* d_ws, size_t ws_size,
                              hipStream_t stream) {
  const float* x  = (const float*)d_in[0];
  const float* wq = (const float*)d_in[1];
  const float* bq = (const float*)d_in[2];
  const float* wk = (const float*)d_in[3];
  const float* bk = (const float*)d_in[4];
  const float* wv = (const float*)d_in[5];
  const float* bv = (const float*)d_in[6];
  const float* gp = (const float*)d_in[7];
  const float* gc = (const float*)d_in[8];
  float* out = (float*)d_out;

  float* ws = (float*)d_ws;
  size_t o = 0;
  float* pamT  = ws + o; o += (size_t)B_ * N_ * C_;     // 2097152
  float* lsum  = ws + o; o += (size_t)2 * B_ * N_;      // 16384 (8192 used)
  float* lp    = ws + o; o += (size_t)2 * B_ * N_;      // 16384 (unused, layout kept)
  float* eCp   = ws + o; o += (size_t)8 * B_ * C_ * C_; // 1048576
  bf16*  ahi   = (bf16*)(ws + o); o += (size_t)B_ * C_ * C_ / 2;   // 65536 fl
  bf16*  alo   = (bf16*)(ws + o); o += (size_t)B_ * C_ * C_ / 2;   // 65536 fl
  bf16*  vbf   = (bf16*)(ws + o); o += (size_t)B_ * N_ * C_ / 2;   // 1048576
  bf16*  qhi   = (bf16*)(ws + o); o += (size_t)B_ * N_ * QK_ / 2;  // 131072
  bf16*  qlo   = (bf16*)(ws + o); o += (size_t)B_ * N_ * QK_ / 2;  // 131072
  bf16*  khi   = (bf16*)(ws + o); o += (size_t)B_ * N_ * QK_ / 2;  // 131072
  bf16*  klo   = (bf16*)(ws + o); o += (size_t)B_ * N_ * QK_ / 2;  // 131072
  float* xtbuf = ws + o; o += (size_t)2 * B_ * N_ * QK_ * 4;       // 2097152 (xT hi/lo)
  bf16* xthi = (bf16*)xtbuf;
  bf16* xtlo = (bf16*)(xtbuf + (size_t)B_ * N_ * C_ / 2);
  // weight hi/lo buffers alias eCp (dead until k_ce2; k_qkp/k_vbf2 run first)
  bf16* wqkh = (bf16*)eCp;
  bf16* wqkl = wqkh + (size_t)64 * C_;
  bf16* wvh  = wqkl + (size_t)64 * C_;
  bf16* wvl  = wvh + (size_t)C_ * C_;
  // x [b][c][n] hi/lo alias pamT (dead until k_cs zeroes it; k_ce2 reads first)
  bf16* xchi = (bf16*)pamT;
  bf16* xclo = xchi + (size_t)B_ * C_ * N_;     // 2x 1M floats = exact fit
  (void)lp;
  // total ~6.8 M floats = 27.4 MB (unchanged)

  k_wcv<<<dim3((64 * C_ + C_ * C_) / 256), dim3(256), 0, stream>>>(wq, wk, wv, wqkh, wqkl, wvh, wvl);
  k_xt<<<dim3(N_ / 64, C_ / 64, B_), dim3(256), 0, stream>>>(x, xthi, xtlo, xchi, xclo);
  k_qkp<<<dim3(N_ / 128, B_), dim3(256), 0, stream>>>(xthi, xtlo, wqkh, wqkl, bq, bk, qhi, qlo, khi, klo);
  k_vbf2<<<dim3(N_ / 32, B_), dim3(256), 0, stream>>>(xthi, xtlo, wvh, wvl, bv, vbf);
  k_ce2<<<dim3(C_ / 32, 8, B_), dim3(256), 0, stream>>>(xchi, xclo, eCp);
  k_cs<<<dim3(B_ * C_), dim3(256), 0, stream>>>(eCp, ahi, alo, pamT, lsum);
  k_pbm<<<dim3(N_ / 64, 2, B_), dim3(512), 0, stream>>>(qhi, qlo, khi, klo, vbf, pamT, lsum);
  k_cam<<<dim3(N_ / 32, B_), dim3(512), 0, stream>>>(xthi, xtlo, ahi, alo, pamT, lsum, x, gp, gc, out);
}

// Round 16
// 193.906 us; speedup vs baseline: 1.1584x; 1.0895x over previous
//
#include <hip/hip_runtime.h>
#include <hip/hip_bf16.h>

// DA block (DANet) — Round 32: revert to R29-green + hi-only k_cam.
// R31 post-mortem: k_pbm is at a ~52 µs load-latency floor (0.79x MFMA and
// 0.85x loads -> same time); reshapes can't move it; atomics cost ~9 µs.
// Trim with error budget: cam = sum_j a_j x_j, sum(a)=1 -> dropping lo-terms
// adds <= 0.004 abs (15x below the 0.0625 PAM floor). k_cam: 1 MFMA (hi*hi),
// half the fragment loads. k_cs: no alo. All else = R29-green.

#define B_ 2
#define C_ 256
#define N_ 4096
#define QK_ 32

#define TJ_ 128    // j per tile (8 waves x 16)
#define PPB_ 136   // p LDS pitch (bf16) = 272 B (16B-aligned rows)

typedef __hip_bfloat16 bf16;
typedef __attribute__((ext_vector_type(8))) short bf16x8f;   // MFMA A/B frag
typedef __attribute__((ext_vector_type(4))) float f32x4;     // MFMA C/D frag

union bf8pack { bf16 h[8]; int4 v; bf16x8f f; };
union bf4pack { bf16 h[4]; uint2 u; };

// ---- k_wcv: weights -> hi/lo bf16. wqk = [wq;wk] 64x256, wv 256x256 ----
__global__ __launch_bounds__(256) void k_wcv(
    const float* __restrict__ wq, const float* __restrict__ wk, const float* __restrict__ wv,
    bf16* __restrict__ wqkh, bf16* __restrict__ wqkl,
    bf16* __restrict__ wvh, bf16* __restrict__ wvl) {
  int idx = blockIdx.x * 256 + threadIdx.x;
  if (idx < 64 * C_) {
    int r = idx >> 8, c = idx & 255;
    float v = (r < 32) ? wq[r * C_ + c] : wk[(r - 32) * C_ + c];
    bf16 h = __float2bfloat16(v);
    wqkh[idx] = h; wqkl[idx] = __float2bfloat16(v - __bfloat162float(h));
  } else {
    int j = idx - 64 * C_;
    float v = wv[j];
    bf16 h = __float2bfloat16(v);
    wvh[j] = h; wvl[j] = __float2bfloat16(v - __bfloat162float(h));
  }
}

// ---- k_xt v2: x -> xT hi/lo [b][n][c] AND xc hi/lo [b][c][n] ----
__global__ __launch_bounds__(256) void k_xt(
    const float* __restrict__ x, bf16* __restrict__ xthi, bf16* __restrict__ xtlo,
    bf16* __restrict__ xchi, bf16* __restrict__ xclo) {
  int b = blockIdx.z;
  int c0 = blockIdx.y * 64;
  int n0 = blockIdx.x * 64;
  __shared__ float t[64 * 65];
  int tid = threadIdx.x;
  int col = tid & 63, rowq = tid >> 6;        // 4 rows per pass
#pragma unroll
  for (int k = 0; k < 16; k++) {
    int r = k * 4 + rowq;
    size_t src = ((size_t)b * C_ + c0 + r) * N_ + n0 + col;
    float v = x[src];
    t[r * 65 + col] = v;
    bf16 h = __float2bfloat16(v);            // same-layout bf16 hi/lo
    xchi[src] = h;
    xclo[src] = __float2bfloat16(v - __bfloat162float(h));
  }
  __syncthreads();
#pragma unroll
  for (int k = 0; k < 16; k++) {
    int nrow = k * 4 + rowq;
    float v = t[col * 65 + nrow];             // [c_local=col][n_local=nrow]
    bf16 h = __float2bfloat16(v);
    size_t o = ((size_t)b * N_ + n0 + nrow) * C_ + c0 + col;
    xthi[o] = h;
    xtlo[o] = __float2bfloat16(v - __bfloat162float(h));
  }
}

// ---- k_qkp: q/k proj via MFMA. A=wqk (rows o), B=xT (rows n), K=256 ----
__global__ __launch_bounds__(256) void k_qkp(
    const bf16* __restrict__ xthi, const bf16* __restrict__ xtlo,
    const bf16* __restrict__ wqkh, const bf16* __restrict__ wqkl,
    const float* __restrict__ bq, const float* __restrict__ bk,
    bf16* __restrict__ qhi, bf16* __restrict__ qlo,
    bf16* __restrict__ khi, bf16* __restrict__ klo) {
  int b = blockIdx.y;
  int tid = threadIdx.x;
  int lane = tid & 63, wave = tid >> 6;
  int n16 = lane & 15, quad = lane >> 4;
  int nb = blockIdx.x * 128 + wave * 32;

  f32x4 acc[4][2];                              // [ot][nt]
#pragma unroll
  for (int ot = 0; ot < 4; ot++)
#pragma unroll
    for (int nt = 0; nt < 2; nt++) acc[ot][nt] = (f32x4)(0.f);

#pragma unroll
  for (int kk = 0; kk < 8; kk++) {
    bf16x8f Ah[4], Al[4], Bh[2], Bl[2];
#pragma unroll
    for (int ot = 0; ot < 4; ot++) {
      size_t off = (size_t)(ot * 16 + n16) * C_ + kk * 32 + quad * 8;
      Ah[ot] = *(const bf16x8f*)(const void*)(wqkh + off);
      Al[ot] = *(const bf16x8f*)(const void*)(wqkl + off);
    }
#pragma unroll
    for (int nt = 0; nt < 2; nt++) {
      size_t off = ((size_t)b * N_ + nb + nt * 16 + n16) * C_ + kk * 32 + quad * 8;
      Bh[nt] = *(const bf16x8f*)(const void*)(xthi + off);
      Bl[nt] = *(const bf16x8f*)(const void*)(xtlo + off);
    }
#pragma unroll
    for (int ot = 0; ot < 4; ot++)
#pragma unroll
      for (int nt = 0; nt < 2; nt++) {
        acc[ot][nt] = __builtin_amdgcn_mfma_f32_16x16x32_bf16(Ah[ot], Bh[nt], acc[ot][nt], 0, 0, 0);
        acc[ot][nt] = __builtin_amdgcn_mfma_f32_16x16x32_bf16(Al[ot], Bh[nt], acc[ot][nt], 0, 0, 0);
        acc[ot][nt] = __builtin_amdgcn_mfma_f32_16x16x32_bf16(Ah[ot], Bl[nt], acc[ot][nt], 0, 0, 0);
      }
  }
#pragma unroll
  for (int ot = 0; ot < 4; ot++)
#pragma unroll
    for (int nt = 0; nt < 2; nt++) {
      int n = nb + nt * 16 + n16;
      int o0 = (ot & 1) * 16 + quad * 4;        // o within q or k (0..31)
      bf4pack ph, pl;
#pragma unroll
      for (int r = 0; r < 4; r++) {
        float v = acc[ot][nt][r] + (ot < 2 ? bq[o0 + r] : bk[o0 + r]);
        bf16 h = __float2bfloat16(v);
        ph.h[r] = h; pl.h[r] = __float2bfloat16(v - __bfloat162float(h));
      }
      size_t base = ((size_t)b * N_ + n) * QK_ + o0;
      if (ot < 2) { *(uint2*)(qhi + base) = ph.u; *(uint2*)(qlo + base) = pl.u; }
      else        { *(uint2*)(khi + base) = ph.u; *(uint2*)(klo + base) = pl.u; }
    }
}

// ---- k_vbf2: V proj via MFMA. A=wv (rows c), B=xT (rows n), K=256 ----
__global__ __launch_bounds__(256) void k_vbf2(
    const bf16* __restrict__ xthi, const bf16* __restrict__ xtlo,
    const bf16* __restrict__ wvh, const bf16* __restrict__ wvl,
    const float* __restrict__ bv, bf16* __restrict__ vbf) {
  int b = blockIdx.y;
  int n0 = blockIdx.x * 32;
  int tid = threadIdx.x;
  int lane = tid & 63, wave = tid >> 6;
  int n16 = lane & 15, quad = lane >> 4;
  int c0 = wave * 64;

  f32x4 acc[4][2];                              // [ct][nt]
#pragma unroll
  for (int ct = 0; ct < 4; ct++)
#pragma unroll
    for (int nt = 0; nt < 2; nt++) acc[ct][nt] = (f32x4)(0.f);

#pragma unroll
  for (int kk = 0; kk < 8; kk++) {
    bf16x8f Ah[4], Al[4], Bh[2], Bl[2];
#pragma unroll
    for (int ct = 0; ct < 4; ct++) {
      size_t off = (size_t)(c0 + ct * 16 + n16) * C_ + kk * 32 + quad * 8;
      Ah[ct] = *(const bf16x8f*)(const void*)(wvh + off);
      Al[ct] = *(const bf16x8f*)(const void*)(wvl + off);
    }
#pragma unroll
    for (int nt = 0; nt < 2; nt++) {
      size_t off = ((size_t)b * N_ + n0 + nt * 16 + n16) * C_ + kk * 32 + quad * 8;
      Bh[nt] = *(const bf16x8f*)(const void*)(xthi + off);
      Bl[nt] = *(const bf16x8f*)(const void*)(xtlo + off);
    }
#pragma unroll
    for (int ct = 0; ct < 4; ct++)
#pragma unroll
      for (int nt = 0; nt < 2; nt++) {
        acc[ct][nt] = __builtin_amdgcn_mfma_f32_16x16x32_bf16(Ah[ct], Bh[nt], acc[ct][nt], 0, 0, 0);
        acc[ct][nt] = __builtin_amdgcn_mfma_f32_16x16x32_bf16(Al[ct], Bh[nt], acc[ct][nt], 0, 0, 0);
        acc[ct][nt] = __builtin_amdgcn_mfma_f32_16x16x32_bf16(Ah[ct], Bl[nt], acc[ct][nt], 0, 0, 0);
      }
  }
#pragma unroll
  for (int ct = 0; ct < 4; ct++)
#pragma unroll
    for (int nt = 0; nt < 2; nt++) {
      int n = n0 + nt * 16 + n16;
      int cb = c0 + ct * 16 + quad * 4;
#pragma unroll
      for (int r = 0; r < 4; r++) {
        float v = acc[ct][nt][r] + bv[cb + r];
        vbf[((size_t)b * C_ + cb + r) * N_ + n] = __float2bfloat16(v);
      }
    }
}

// ---- k_pbm v13: single-pass flash-no-max (R29-green) ----
__global__ __launch_bounds__(512) void k_pbm(
    const bf16* __restrict__ qhi, const bf16* __restrict__ qlo,
    const bf16* __restrict__ khi, const bf16* __restrict__ klo,
    const bf16* __restrict__ vbf,
    float* __restrict__ pamT) {
  int b = blockIdx.z;
  int h0 = blockIdx.y * 128;                     // channel half
  int i0 = blockIdx.x * 64;
  int tid = threadIdx.x;
  int lane = tid & 63, wave = tid >> 6;
  int n16 = lane & 15, quad = lane >> 4;

  __shared__ __align__(16) bf16 p_s[2][64 * PPB_];   // 34.8 KB double-buffered

  bf16x8f ahf[4], alf[4];
#pragma unroll
  for (int ih = 0; ih < 4; ih++) {
    size_t qoff = ((size_t)b * N_ + i0 + ih * 16 + n16) * QK_ + quad * 8;
    ahf[ih] = *(const bf16x8f*)(const void*)(qhi + qoff);
    alf[ih] = *(const bf16x8f*)(const void*)(qlo + qoff);
  }

  f32x4 acc[4];
  float l16[16];                                 // per-lane partial denominators
#pragma unroll
  for (int ih = 0; ih < 4; ih++) acc[ih] = (f32x4)(0.f);
#pragma unroll
  for (int k = 0; k < 16; k++) l16[k] = 0.f;

  const bf16* khb = khi + ((size_t)b * N_ + wave * 16 + n16) * QK_ + quad * 8;
  const bf16* klb = klo + ((size_t)b * N_ + wave * 16 + n16) * QK_ + quad * 8;
  const bf16* vb0 = vbf + ((size_t)b * C_ + h0 + wave * 16 + n16) * N_ + quad * 8;

  const int NJT = N_ / TJ_;                      // 32 iterations

  // ---- prologue: produce P(0); load K(1), V(0) ----
  bf16x8f khf = *(const bf16x8f*)(const void*)khb;
  bf16x8f klf = *(const bf16x8f*)(const void*)klb;
  {
    bf16* pbuf = p_s[0];
#pragma unroll
    for (int ih = 0; ih < 4; ih++) {
      f32x4 t = (f32x4)(0.f);
      t = __builtin_amdgcn_mfma_f32_16x16x32_bf16(ahf[ih], khf, t, 0, 0, 0);
      t = __builtin_amdgcn_mfma_f32_16x16x32_bf16(alf[ih], khf, t, 0, 0, 0);
      t = __builtin_amdgcn_mfma_f32_16x16x32_bf16(ahf[ih], klf, t, 0, 0, 0);
#pragma unroll
      for (int r = 0; r < 4; r++) {
        int i = ih * 16 + quad * 4 + r;
        float p = __expf(t[r]);
        l16[ih * 4 + r] += p;
        pbuf[i * PPB_ + wave * 16 + n16] = __float2bfloat16(p);
      }
    }
  }
  khf = *(const bf16x8f*)(const void*)(khb + (size_t)TJ_ * QK_);
  klf = *(const bf16x8f*)(const void*)(klb + (size_t)TJ_ * QK_);
  bf16x8f vcur[4];
#pragma unroll
  for (int jhh = 0; jhh < 4; jhh++)
    vcur[jhh] = *(const bf16x8f*)(const void*)(vb0 + jhh * 32);
  __syncthreads();                               // P(0) visible

  for (int jt = 0; jt < NJT; jt++) {
    f32x4 z[4];
    if (jt + 1 < NJT) {
#pragma unroll
      for (int ih = 0; ih < 4; ih++) {
        f32x4 t = (f32x4)(0.f);
        t = __builtin_amdgcn_mfma_f32_16x16x32_bf16(ahf[ih], khf, t, 0, 0, 0);
        t = __builtin_amdgcn_mfma_f32_16x16x32_bf16(alf[ih], khf, t, 0, 0, 0);
        t = __builtin_amdgcn_mfma_f32_16x16x32_bf16(ahf[ih], klf, t, 0, 0, 0);
        z[ih] = t;
      }
    }
    {
      const bf16* pbuf = p_s[jt & 1];
#pragma unroll
      for (int jhh = 0; jhh < 4; jhh++) {
        bf16x8f pa[4];
#pragma unroll
        for (int ih = 0; ih < 4; ih++)
          pa[ih] = *(const bf16x8f*)(const void*)(pbuf + (ih * 16 + n16) * PPB_ + jhh * 32 + quad * 8);
#pragma unroll
        for (int ih = 0; ih < 4; ih++)
          acc[ih] = __builtin_amdgcn_mfma_f32_16x16x32_bf16(pa[ih], vcur[jhh], acc[ih], 0, 0, 0);
      }
    }
    if (jt + 1 < NJT) {
      bf16* pbuf = p_s[(jt + 1) & 1];
#pragma unroll
      for (int ih = 0; ih < 4; ih++)
#pragma unroll
        for (int r = 0; r < 4; r++) {
          int i = ih * 16 + quad * 4 + r;
          float p = __expf(z[ih][r]);
          l16[ih * 4 + r] += p;
          pbuf[i * PPB_ + wave * 16 + n16] = __float2bfloat16(p);
        }
    }
    bf16x8f khn, kln, vnxt[4];
    if (jt + 2 < NJT) {
      size_t koff = (size_t)(jt + 2) * TJ_ * QK_;
      khn = *(const bf16x8f*)(const void*)(khb + koff);
      kln = *(const bf16x8f*)(const void*)(klb + koff);
    }
    if (jt + 1 < NJT) {
      int jb = (jt + 1) * TJ_;
#pragma unroll
      for (int jhh = 0; jhh < 4; jhh++)
        vnxt[jhh] = *(const bf16x8f*)(const void*)(vb0 + jb + jhh * 32);
    }
    __syncthreads();
    khf = khn; klf = kln;
#pragma unroll
    for (int jhh = 0; jhh < 4; jhh++) vcur[jhh] = vnxt[jhh];
  }

  // ---- epilogue: reduce l over 16 n16-lanes, then 8 waves; scale+store ----
#pragma unroll
  for (int d = 1; d < 16; d <<= 1)
#pragma unroll
    for (int k = 0; k < 16; k++)
      l16[k] += __shfl_xor(l16[k], d, 64);
  float* red = (float*)p_s;                      // 8*64 + 64 floats, aliases p_s
  float* linv = red + 8 * 64;
  if (n16 == 0) {
#pragma unroll
    for (int ih = 0; ih < 4; ih++)
#pragma unroll
      for (int r = 0; r < 4; r++)
        red[wave * 64 + ih * 16 + quad * 4 + r] = l16[ih * 4 + r];
  }
  __syncthreads();
  if (tid < 64) {
    float L = 0.f;
#pragma unroll
    for (int w = 0; w < 8; w++) L += red[w * 64 + tid];
    linv[tid] = 1.0f / L;
  }
  __syncthreads();
  int c = h0 + wave * 16 + n16;
#pragma unroll
  for (int ih = 0; ih < 4; ih++)
#pragma unroll
    for (int r = 0; r < 4; r++) {
      int i = ih * 16 + quad * 4 + r;
      pamT[((size_t)b * N_ + i0 + i) * C_ + c] = acc[ih][r] * linv[i];
    }
}

// ---- k_ce2: CAM energy via MFMA hi/lo. e_p[kc][b][i][j] partials ----
__global__ __launch_bounds__(256) void k_ce2(
    const bf16* __restrict__ xchi, const bf16* __restrict__ xclo,
    float* __restrict__ eCp) {
  int b = blockIdx.z;
  int kc = blockIdx.y;
  int i0 = blockIdx.x * 32;
  int tid = threadIdx.x;
  int lane = tid & 63, wave = tid >> 6;
  int n16 = lane & 15, quad = lane >> 4;
  int j0 = wave * 64;

  f32x4 acc[2][4];                               // [it][jt]
#pragma unroll
  for (int it = 0; it < 2; it++)
#pragma unroll
    for (int jt = 0; jt < 4; jt++) acc[it][jt] = (f32x4)(0.f);

  size_t kb = (size_t)kc * 512;
#pragma unroll 2
  for (int kk = 0; kk < 16; kk++) {
    bf16x8f Ah[2], Al[2], Bh[4], Bl[4];
#pragma unroll
    for (int it = 0; it < 2; it++) {
      size_t off = ((size_t)b * C_ + i0 + it * 16 + n16) * N_ + kb + kk * 32 + quad * 8;
      Ah[it] = *(const bf16x8f*)(const void*)(xchi + off);
      Al[it] = *(const bf16x8f*)(const void*)(xclo + off);
    }
#pragma unroll
    for (int jt = 0; jt < 4; jt++) {
      size_t off = ((size_t)b * C_ + j0 + jt * 16 + n16) * N_ + kb + kk * 32 + quad * 8;
      Bh[jt] = *(const bf16x8f*)(const void*)(xchi + off);
      Bl[jt] = *(const bf16x8f*)(const void*)(xclo + off);
    }
#pragma unroll
    for (int it = 0; it < 2; it++)
#pragma unroll
      for (int jt = 0; jt < 4; jt++) {
        acc[it][jt] = __builtin_amdgcn_mfma_f32_16x16x32_bf16(Ah[it], Bh[jt], acc[it][jt], 0, 0, 0);
        acc[it][jt] = __builtin_amdgcn_mfma_f32_16x16x32_bf16(Al[it], Bh[jt], acc[it][jt], 0, 0, 0);
        acc[it][jt] = __builtin_amdgcn_mfma_f32_16x16x32_bf16(Ah[it], Bl[jt], acc[it][jt], 0, 0, 0);
      }
  }
  float* dst = eCp + ((size_t)kc * B_ + b) * C_ * C_;
#pragma unroll
  for (int it = 0; it < 2; it++)
#pragma unroll
    for (int jt = 0; jt < 4; jt++) {
      int i = i0 + it * 16 + quad * 4;
      int j = j0 + jt * 16 + n16;
#pragma unroll
      for (int r = 0; r < 4; r++)
        dst[(size_t)(i + r) * C_ + j] = acc[it][jt][r];
    }
}

// ---- k_cs v4: CAM softmax over -e; emit bf16 hi ONLY ----
__global__ __launch_bounds__(256) void k_cs(
    const float* __restrict__ eCp, bf16* __restrict__ ahi) {
  int row = blockIdx.x;
  int b = row >> 8, i = row & 255;
  int j = threadIdx.x;
  float e = 0.f;
#pragma unroll
  for (int kc = 0; kc < 8; kc++) e += eCp[(((size_t)kc * B_ + b) * C_ + i) * C_ + j];
  float ne = -e;
  __shared__ float buf[256];
  buf[j] = ne;
  __syncthreads();
  for (int st = 128; st >= 1; st >>= 1) {
    if (j < st) buf[j] = fmaxf(buf[j], buf[j + st]);
    __syncthreads();
  }
  float m = buf[0];
  __syncthreads();
  float p = __expf(ne - m);
  buf[j] = p;
  __syncthreads();
  for (int st = 128; st >= 1; st >>= 1) {
    if (j < st) buf[j] += buf[j + st];
    __syncthreads();
  }
  ahi[(size_t)row * C_ + j] = __float2bfloat16(p / buf[0]);
}

// ---- k_cam v5: hi-only (1 MFMA): cam err <= ~0.004 << 0.0625 floor.
//      fused: out = gp*pamT + gc*cam + 2x. grid (N/32, B), 512 thr ----
__global__ __launch_bounds__(512) void k_cam(
    const bf16* __restrict__ xthi,
    const bf16* __restrict__ ahi,
    const float* __restrict__ pamT, const float* __restrict__ x,
    const float* __restrict__ gpam, const float* __restrict__ gcam,
    float* __restrict__ out) {
  int b = blockIdx.y;
  int n0 = blockIdx.x * 32;
  int tid = threadIdx.x;
  int lane = tid & 63, wave = tid >> 6;
  int n16 = lane & 15, quad = lane >> 4;
  int c0 = wave * 32;

  f32x4 acc[2][2];                               // [nt][ct]
#pragma unroll
  for (int nt = 0; nt < 2; nt++)
#pragma unroll
    for (int ct = 0; ct < 2; ct++) acc[nt][ct] = (f32x4)(0.f);

#pragma unroll
  for (int kk = 0; kk < 8; kk++) {               // K = 256 = 8 x 32
    bf16x8f Ah[2], Bh[2];
#pragma unroll
    for (int nt = 0; nt < 2; nt++) {
      size_t off = ((size_t)b * N_ + n0 + nt * 16 + n16) * C_ + kk * 32 + quad * 8;
      Ah[nt] = *(const bf16x8f*)(const void*)(xthi + off);
    }
#pragma unroll
    for (int ct = 0; ct < 2; ct++) {
      size_t off = ((size_t)b * C_ + c0 + ct * 16 + n16) * C_ + kk * 32 + quad * 8;
      Bh[ct] = *(const bf16x8f*)(const void*)(ahi + off);
    }
#pragma unroll
    for (int nt = 0; nt < 2; nt++)
#pragma unroll
      for (int ct = 0; ct < 2; ct++)
        acc[nt][ct] = __builtin_amdgcn_mfma_f32_16x16x32_bf16(Ah[nt], Bh[ct], acc[nt][ct], 0, 0, 0);
  }
  float gp = gpam[0], gc = gcam[0];
#pragma unroll
  for (int nt = 0; nt < 2; nt++)
#pragma unroll
    for (int ct = 0; ct < 2; ct++) {
      int c = c0 + ct * 16 + n16;
      int nb = n0 + nt * 16 + quad * 4;
      const float* xp = x + ((size_t)b * C_ + c) * N_ + nb;
      float4 x4 = *(const float4*)(const void*)xp;
      float4 o4;
      o4.x = gp * pamT[((size_t)b * N_ + nb + 0) * C_ + c] + gc * acc[nt][ct][0] + 2.0f * x4.x;
      o4.y = gp * pamT[((size_t)b * N_ + nb + 1) * C_ + c] + gc * acc[nt][ct][1] + 2.0f * x4.y;
      o4.z = gp * pamT[((size_t)b * N_ + nb + 2) * C_ + c] + gc * acc[nt][ct][2] + 2.0f * x4.z;
      o4.w = gp * pamT[((size_t)b * N_ + nb + 3) * C_ + c] + gc * acc[nt][ct][3] + 2.0f * x4.w;
      *(float4*)(out + ((size_t)b * C_ + c) * N_ + nb) = o4;
    }
}

extern "C" void kernel_launch(void* const* d_in, const int* in_sizes, int n_in,
                              void* d_out, int out_size, void* d_ws, size_t ws_size,
                              hipStream_t stream) {
  const float* x  = (const float*)d_in[0];
  const float* wq = (const float*)d_in[1];
  const float* bq = (const float*)d_in[2];
  const float* wk = (const float*)d_in[3];
  const float* bk = (const float*)d_in[4];
  const float* wv = (const float*)d_in[5];
  const float* bv = (const float*)d_in[6];
  const float* gp = (const float*)d_in[7];
  const float* gc = (const float*)d_in[8];
  float* out = (float*)d_out;

  float* ws = (float*)d_ws;
  size_t o = 0;
  float* pamT  = ws + o; o += (size_t)B_ * N_ * C_;     // 2097152
  float* mp    = ws + o; o += (size_t)2 * B_ * N_;      // 16384 (unused, layout kept)
  float* lp    = ws + o; o += (size_t)2 * B_ * N_;      // 16384 (unused, layout kept)
  float* eCp   = ws + o; o += (size_t)8 * B_ * C_ * C_; // 1048576
  bf16*  ahi   = (bf16*)(ws + o); o += (size_t)B_ * C_ * C_ / 2;   // 65536 fl
  bf16*  alo   = (bf16*)(ws + o); o += (size_t)B_ * C_ * C_ / 2;   // 65536 fl (unused)
  bf16*  vbf   = (bf16*)(ws + o); o += (size_t)B_ * N_ * C_ / 2;   // 1048576
  bf16*  qhi   = (bf16*)(ws + o); o += (size_t)B_ * N_ * QK_ / 2;  // 131072
  bf16*  qlo   = (bf16*)(ws + o); o += (size_t)B_ * N_ * QK_ / 2;  // 131072
  bf16*  khi   = (bf16*)(ws + o); o += (size_t)B_ * N_ * QK_ / 2;  // 131072
  bf16*  klo   = (bf16*)(ws + o); o += (size_t)B_ * N_ * QK_ / 2;  // 131072
  float* xtbuf = ws + o; o += (size_t)2 * B_ * N_ * QK_ * 4;       // 2097152 (xT hi/lo)
  bf16* xthi = (bf16*)xtbuf;
  bf16* xtlo = (bf16*)(xtbuf + (size_t)B_ * N_ * C_ / 2);
  // weight hi/lo buffers alias eCp (dead until k_ce2; k_qkp/k_vbf2 run first)
  bf16* wqkh = (bf16*)eCp;
  bf16* wqkl = wqkh + (size_t)64 * C_;
  bf16* wvh  = wqkl + (size_t)64 * C_;
  bf16* wvl  = wvh + (size_t)C_ * C_;
  // x [b][c][n] hi/lo alias pamT (dead until k_pbm; k_ce2/k_cs run before)
  bf16* xchi = (bf16*)pamT;
  bf16* xclo = xchi + (size_t)B_ * C_ * N_;     // 2x 1M floats = exact fit
  (void)mp; (void)lp; (void)alo;
  // total ~6.8 M floats = 27.4 MB (unchanged)

  k_wcv<<<dim3((64 * C_ + C_ * C_) / 256), dim3(256), 0, stream>>>(wq, wk, wv, wqkh, wqkl, wvh, wvl);
  k_xt<<<dim3(N_ / 64, C_ / 64, B_), dim3(256), 0, stream>>>(x, xthi, xtlo, xchi, xclo);
  k_qkp<<<dim3(N_ / 128, B_), dim3(256), 0, stream>>>(xthi, xtlo, wqkh, wqkl, bq, bk, qhi, qlo, khi, klo);
  k_vbf2<<<dim3(N_ / 32, B_), dim3(256), 0, stream>>>(xthi, xtlo, wvh, wvl, bv, vbf);
  k_ce2<<<dim3(C_ / 32, 8, B_), dim3(256), 0, stream>>>(xchi, xclo, eCp);
  k_cs<<<dim3(B_ * C_), dim3(256), 0, stream>>>(eCp, ahi);
  k_pbm<<<dim3(N_ / 64, 2, B_), dim3(512), 0, stream>>>(qhi, qlo, khi, klo, vbf, pamT);
  k_cam<<<dim3(N_ / 32, B_), dim3(512), 0, stream>>>(xthi, ahi, pamT, x, gp, gc, out);
}

// Round 17
// 179.556 us; speedup vs baseline: 1.2509x; 1.0799x over previous
//
#include <hip/hip_runtime.h>
#include <hip/hip_bf16.h>

// DA block (DANet) — Round 33: occupancy fixes for k_qkp (64->256 blocks)
// and k_ce2 (128->256 blocks, j-half split; per-block traffic 576->320 KB).
// Both keep per-output MFMA chains identical -> outputs bit-identical.
// k_pbm at its ~52-55 µs latency floor (settled). All else = R32-green.

#define B_ 2
#define C_ 256
#define N_ 4096
#define QK_ 32

#define TJ_ 128    // j per tile (8 waves x 16)
#define PPB_ 136   // p LDS pitch (bf16) = 272 B (16B-aligned rows)

typedef __hip_bfloat16 bf16;
typedef __attribute__((ext_vector_type(8))) short bf16x8f;   // MFMA A/B frag
typedef __attribute__((ext_vector_type(4))) float f32x4;     // MFMA C/D frag

union bf8pack { bf16 h[8]; int4 v; bf16x8f f; };
union bf4pack { bf16 h[4]; uint2 u; };

// ---- k_wcv: weights -> hi/lo bf16. wqk = [wq;wk] 64x256, wv 256x256 ----
__global__ __launch_bounds__(256) void k_wcv(
    const float* __restrict__ wq, const float* __restrict__ wk, const float* __restrict__ wv,
    bf16* __restrict__ wqkh, bf16* __restrict__ wqkl,
    bf16* __restrict__ wvh, bf16* __restrict__ wvl) {
  int idx = blockIdx.x * 256 + threadIdx.x;
  if (idx < 64 * C_) {
    int r = idx >> 8, c = idx & 255;
    float v = (r < 32) ? wq[r * C_ + c] : wk[(r - 32) * C_ + c];
    bf16 h = __float2bfloat16(v);
    wqkh[idx] = h; wqkl[idx] = __float2bfloat16(v - __bfloat162float(h));
  } else {
    int j = idx - 64 * C_;
    float v = wv[j];
    bf16 h = __float2bfloat16(v);
    wvh[j] = h; wvl[j] = __float2bfloat16(v - __bfloat162float(h));
  }
}

// ---- k_xt v2: x -> xT hi/lo [b][n][c] AND xc hi/lo [b][c][n] ----
__global__ __launch_bounds__(256) void k_xt(
    const float* __restrict__ x, bf16* __restrict__ xthi, bf16* __restrict__ xtlo,
    bf16* __restrict__ xchi, bf16* __restrict__ xclo) {
  int b = blockIdx.z;
  int c0 = blockIdx.y * 64;
  int n0 = blockIdx.x * 64;
  __shared__ float t[64 * 65];
  int tid = threadIdx.x;
  int col = tid & 63, rowq = tid >> 6;        // 4 rows per pass
#pragma unroll
  for (int k = 0; k < 16; k++) {
    int r = k * 4 + rowq;
    size_t src = ((size_t)b * C_ + c0 + r) * N_ + n0 + col;
    float v = x[src];
    t[r * 65 + col] = v;
    bf16 h = __float2bfloat16(v);            // same-layout bf16 hi/lo
    xchi[src] = h;
    xclo[src] = __float2bfloat16(v - __bfloat162float(h));
  }
  __syncthreads();
#pragma unroll
  for (int k = 0; k < 16; k++) {
    int nrow = k * 4 + rowq;
    float v = t[col * 65 + nrow];             // [c_local=col][n_local=nrow]
    bf16 h = __float2bfloat16(v);
    size_t o = ((size_t)b * N_ + n0 + nrow) * C_ + c0 + col;
    xthi[o] = h;
    xtlo[o] = __float2bfloat16(v - __bfloat162float(h));
  }
}

// ---- k_qkp v2: 256 blocks. Wave = 16-o tile x 32 n. Bit-identical q/k ----
__global__ __launch_bounds__(256) void k_qkp(
    const bf16* __restrict__ xthi, const bf16* __restrict__ xtlo,
    const bf16* __restrict__ wqkh, const bf16* __restrict__ wqkl,
    const float* __restrict__ bq, const float* __restrict__ bk,
    bf16* __restrict__ qhi, bf16* __restrict__ qlo,
    bf16* __restrict__ khi, bf16* __restrict__ klo) {
  int b = blockIdx.y;
  int tid = threadIdx.x;
  int lane = tid & 63, wave = tid >> 6;        // wave = o-tile 0..3
  int n16 = lane & 15, quad = lane >> 4;
  int nb = blockIdx.x * 32;

  f32x4 acc[2];                                // [nt]
#pragma unroll
  for (int nt = 0; nt < 2; nt++) acc[nt] = (f32x4)(0.f);

#pragma unroll
  for (int kk = 0; kk < 8; kk++) {
    bf16x8f Ah, Al, Bh[2], Bl[2];
    {
      size_t off = (size_t)(wave * 16 + n16) * C_ + kk * 32 + quad * 8;
      Ah = *(const bf16x8f*)(const void*)(wqkh + off);
      Al = *(const bf16x8f*)(const void*)(wqkl + off);
    }
#pragma unroll
    for (int nt = 0; nt < 2; nt++) {
      size_t off = ((size_t)b * N_ + nb + nt * 16 + n16) * C_ + kk * 32 + quad * 8;
      Bh[nt] = *(const bf16x8f*)(const void*)(xthi + off);
      Bl[nt] = *(const bf16x8f*)(const void*)(xtlo + off);
    }
#pragma unroll
    for (int nt = 0; nt < 2; nt++) {
      acc[nt] = __builtin_amdgcn_mfma_f32_16x16x32_bf16(Ah, Bh[nt], acc[nt], 0, 0, 0);
      acc[nt] = __builtin_amdgcn_mfma_f32_16x16x32_bf16(Al, Bh[nt], acc[nt], 0, 0, 0);
      acc[nt] = __builtin_amdgcn_mfma_f32_16x16x32_bf16(Ah, Bl[nt], acc[nt], 0, 0, 0);
    }
  }
#pragma unroll
  for (int nt = 0; nt < 2; nt++) {
    int n = nb + nt * 16 + n16;
    int o0 = (wave & 1) * 16 + quad * 4;       // o within q or k (0..31)
    bf4pack ph, pl;
#pragma unroll
    for (int r = 0; r < 4; r++) {
      float v = acc[nt][r] + (wave < 2 ? bq[o0 + r] : bk[o0 + r]);
      bf16 h = __float2bfloat16(v);
      ph.h[r] = h; pl.h[r] = __float2bfloat16(v - __bfloat162float(h));
    }
    size_t base = ((size_t)b * N_ + n) * QK_ + o0;
    if (wave < 2) { *(uint2*)(qhi + base) = ph.u; *(uint2*)(qlo + base) = pl.u; }
    else          { *(uint2*)(khi + base) = ph.u; *(uint2*)(klo + base) = pl.u; }
  }
}

// ---- k_vbf2: V proj via MFMA. A=wv (rows c), B=xT (rows n), K=256 ----
__global__ __launch_bounds__(256) void k_vbf2(
    const bf16* __restrict__ xthi, const bf16* __restrict__ xtlo,
    const bf16* __restrict__ wvh, const bf16* __restrict__ wvl,
    const float* __restrict__ bv, bf16* __restrict__ vbf) {
  int b = blockIdx.y;
  int n0 = blockIdx.x * 32;
  int tid = threadIdx.x;
  int lane = tid & 63, wave = tid >> 6;
  int n16 = lane & 15, quad = lane >> 4;
  int c0 = wave * 64;

  f32x4 acc[4][2];                              // [ct][nt]
#pragma unroll
  for (int ct = 0; ct < 4; ct++)
#pragma unroll
    for (int nt = 0; nt < 2; nt++) acc[ct][nt] = (f32x4)(0.f);

#pragma unroll
  for (int kk = 0; kk < 8; kk++) {
    bf16x8f Ah[4], Al[4], Bh[2], Bl[2];
#pragma unroll
    for (int ct = 0; ct < 4; ct++) {
      size_t off = (size_t)(c0 + ct * 16 + n16) * C_ + kk * 32 + quad * 8;
      Ah[ct] = *(const bf16x8f*)(const void*)(wvh + off);
      Al[ct] = *(const bf16x8f*)(const void*)(wvl + off);
    }
#pragma unroll
    for (int nt = 0; nt < 2; nt++) {
      size_t off = ((size_t)b * N_ + n0 + nt * 16 + n16) * C_ + kk * 32 + quad * 8;
      Bh[nt] = *(const bf16x8f*)(const void*)(xthi + off);
      Bl[nt] = *(const bf16x8f*)(const void*)(xtlo + off);
    }
#pragma unroll
    for (int ct = 0; ct < 4; ct++)
#pragma unroll
      for (int nt = 0; nt < 2; nt++) {
        acc[ct][nt] = __builtin_amdgcn_mfma_f32_16x16x32_bf16(Ah[ct], Bh[nt], acc[ct][nt], 0, 0, 0);
        acc[ct][nt] = __builtin_amdgcn_mfma_f32_16x16x32_bf16(Al[ct], Bh[nt], acc[ct][nt], 0, 0, 0);
        acc[ct][nt] = __builtin_amdgcn_mfma_f32_16x16x32_bf16(Ah[ct], Bl[nt], acc[ct][nt], 0, 0, 0);
      }
  }
#pragma unroll
  for (int ct = 0; ct < 4; ct++)
#pragma unroll
    for (int nt = 0; nt < 2; nt++) {
      int n = n0 + nt * 16 + n16;
      int cb = c0 + ct * 16 + quad * 4;
#pragma unroll
      for (int r = 0; r < 4; r++) {
        float v = acc[ct][nt][r] + bv[cb + r];
        vbf[((size_t)b * C_ + cb + r) * N_ + n] = __float2bfloat16(v);
      }
    }
}

// ---- k_pbm v13: single-pass flash-no-max (R29-green) ----
__global__ __launch_bounds__(512) void k_pbm(
    const bf16* __restrict__ qhi, const bf16* __restrict__ qlo,
    const bf16* __restrict__ khi, const bf16* __restrict__ klo,
    const bf16* __restrict__ vbf,
    float* __restrict__ pamT) {
  int b = blockIdx.z;
  int h0 = blockIdx.y * 128;                     // channel half
  int i0 = blockIdx.x * 64;
  int tid = threadIdx.x;
  int lane = tid & 63, wave = tid >> 6;
  int n16 = lane & 15, quad = lane >> 4;

  __shared__ __align__(16) bf16 p_s[2][64 * PPB_];   // 34.8 KB double-buffered

  bf16x8f ahf[4], alf[4];
#pragma unroll
  for (int ih = 0; ih < 4; ih++) {
    size_t qoff = ((size_t)b * N_ + i0 + ih * 16 + n16) * QK_ + quad * 8;
    ahf[ih] = *(const bf16x8f*)(const void*)(qhi + qoff);
    alf[ih] = *(const bf16x8f*)(const void*)(qlo + qoff);
  }

  f32x4 acc[4];
  float l16[16];                                 // per-lane partial denominators
#pragma unroll
  for (int ih = 0; ih < 4; ih++) acc[ih] = (f32x4)(0.f);
#pragma unroll
  for (int k = 0; k < 16; k++) l16[k] = 0.f;

  const bf16* khb = khi + ((size_t)b * N_ + wave * 16 + n16) * QK_ + quad * 8;
  const bf16* klb = klo + ((size_t)b * N_ + wave * 16 + n16) * QK_ + quad * 8;
  const bf16* vb0 = vbf + ((size_t)b * C_ + h0 + wave * 16 + n16) * N_ + quad * 8;

  const int NJT = N_ / TJ_;                      // 32 iterations

  // ---- prologue: produce P(0); load K(1), V(0) ----
  bf16x8f khf = *(const bf16x8f*)(const void*)khb;
  bf16x8f klf = *(const bf16x8f*)(const void*)klb;
  {
    bf16* pbuf = p_s[0];
#pragma unroll
    for (int ih = 0; ih < 4; ih++) {
      f32x4 t = (f32x4)(0.f);
      t = __builtin_amdgcn_mfma_f32_16x16x32_bf16(ahf[ih], khf, t, 0, 0, 0);
      t = __builtin_amdgcn_mfma_f32_16x16x32_bf16(alf[ih], khf, t, 0, 0, 0);
      t = __builtin_amdgcn_mfma_f32_16x16x32_bf16(ahf[ih], klf, t, 0, 0, 0);
#pragma unroll
      for (int r = 0; r < 4; r++) {
        int i = ih * 16 + quad * 4 + r;
        float p = __expf(t[r]);
        l16[ih * 4 + r] += p;
        pbuf[i * PPB_ + wave * 16 + n16] = __float2bfloat16(p);
      }
    }
  }
  khf = *(const bf16x8f*)(const void*)(khb + (size_t)TJ_ * QK_);
  klf = *(const bf16x8f*)(const void*)(klb + (size_t)TJ_ * QK_);
  bf16x8f vcur[4];
#pragma unroll
  for (int jhh = 0; jhh < 4; jhh++)
    vcur[jhh] = *(const bf16x8f*)(const void*)(vb0 + jhh * 32);
  __syncthreads();                               // P(0) visible

  for (int jt = 0; jt < NJT; jt++) {
    f32x4 z[4];
    if (jt + 1 < NJT) {
#pragma unroll
      for (int ih = 0; ih < 4; ih++) {
        f32x4 t = (f32x4)(0.f);
        t = __builtin_amdgcn_mfma_f32_16x16x32_bf16(ahf[ih], khf, t, 0, 0, 0);
        t = __builtin_amdgcn_mfma_f32_16x16x32_bf16(alf[ih], khf, t, 0, 0, 0);
        t = __builtin_amdgcn_mfma_f32_16x16x32_bf16(ahf[ih], klf, t, 0, 0, 0);
        z[ih] = t;
      }
    }
    {
      const bf16* pbuf = p_s[jt & 1];
#pragma unroll
      for (int jhh = 0; jhh < 4; jhh++) {
        bf16x8f pa[4];
#pragma unroll
        for (int ih = 0; ih < 4; ih++)
          pa[ih] = *(const bf16x8f*)(const void*)(pbuf + (ih * 16 + n16) * PPB_ + jhh * 32 + quad * 8);
#pragma unroll
        for (int ih = 0; ih < 4; ih++)
          acc[ih] = __builtin_amdgcn_mfma_f32_16x16x32_bf16(pa[ih], vcur[jhh], acc[ih], 0, 0, 0);
      }
    }
    if (jt + 1 < NJT) {
      bf16* pbuf = p_s[(jt + 1) & 1];
#pragma unroll
      for (int ih = 0; ih < 4; ih++)
#pragma unroll
        for (int r = 0; r < 4; r++) {
          int i = ih * 16 + quad * 4 + r;
          float p = __expf(z[ih][r]);
          l16[ih * 4 + r] += p;
          pbuf[i * PPB_ + wave * 16 + n16] = __float2bfloat16(p);
        }
    }
    bf16x8f khn, kln, vnxt[4];
    if (jt + 2 < NJT) {
      size_t koff = (size_t)(jt + 2) * TJ_ * QK_;
      khn = *(const bf16x8f*)(const void*)(khb + koff);
      kln = *(const bf16x8f*)(const void*)(klb + koff);
    }
    if (jt + 1 < NJT) {
      int jb = (jt + 1) * TJ_;
#pragma unroll
      for (int jhh = 0; jhh < 4; jhh++)
        vnxt[jhh] = *(const bf16x8f*)(const void*)(vb0 + jb + jhh * 32);
    }
    __syncthreads();
    khf = khn; klf = kln;
#pragma unroll
    for (int jhh = 0; jhh < 4; jhh++) vcur[jhh] = vnxt[jhh];
  }

  // ---- epilogue: reduce l over 16 n16-lanes, then 8 waves; scale+store ----
#pragma unroll
  for (int d = 1; d < 16; d <<= 1)
#pragma unroll
    for (int k = 0; k < 16; k++)
      l16[k] += __shfl_xor(l16[k], d, 64);
  float* red = (float*)p_s;                      // 8*64 + 64 floats, aliases p_s
  float* linv = red + 8 * 64;
  if (n16 == 0) {
#pragma unroll
    for (int ih = 0; ih < 4; ih++)
#pragma unroll
      for (int r = 0; r < 4; r++)
        red[wave * 64 + ih * 16 + quad * 4 + r] = l16[ih * 4 + r];
  }
  __syncthreads();
  if (tid < 64) {
    float L = 0.f;
#pragma unroll
    for (int w = 0; w < 8; w++) L += red[w * 64 + tid];
    linv[tid] = 1.0f / L;
  }
  __syncthreads();
  int c = h0 + wave * 16 + n16;
#pragma unroll
  for (int ih = 0; ih < 4; ih++)
#pragma unroll
    for (int r = 0; r < 4; r++) {
      int i = ih * 16 + quad * 4 + r;
      pamT[((size_t)b * N_ + i0 + i) * C_ + c] = acc[ih][r] * linv[i];
    }
}

// ---- k_ce2 v2: j-half split -> 256 blocks; per-block traffic 320 KB ----
// grid (16, 8, B): x = i-tile(8) | jh(2)<<3; y = kc. Bit-identical eCp.
__global__ __launch_bounds__(256) void k_ce2(
    const bf16* __restrict__ xchi, const bf16* __restrict__ xclo,
    float* __restrict__ eCp) {
  int b = blockIdx.z;
  int kc = blockIdx.y;
  int it = blockIdx.x & 7, jh = blockIdx.x >> 3;
  int i0 = it * 32;
  int tid = threadIdx.x;
  int lane = tid & 63, wave = tid >> 6;
  int n16 = lane & 15, quad = lane >> 4;
  int j0 = jh * 128 + wave * 32;

  f32x4 acc[2][2];                               // [it2][jt]
#pragma unroll
  for (int it2 = 0; it2 < 2; it2++)
#pragma unroll
    for (int jt = 0; jt < 2; jt++) acc[it2][jt] = (f32x4)(0.f);

  size_t kb = (size_t)kc * 512;
#pragma unroll 2
  for (int kk = 0; kk < 16; kk++) {
    bf16x8f Ah[2], Al[2], Bh[2], Bl[2];
#pragma unroll
    for (int it2 = 0; it2 < 2; it2++) {
      size_t off = ((size_t)b * C_ + i0 + it2 * 16 + n16) * N_ + kb + kk * 32 + quad * 8;
      Ah[it2] = *(const bf16x8f*)(const void*)(xchi + off);
      Al[it2] = *(const bf16x8f*)(const void*)(xclo + off);
    }
#pragma unroll
    for (int jt = 0; jt < 2; jt++) {
      size_t off = ((size_t)b * C_ + j0 + jt * 16 + n16) * N_ + kb + kk * 32 + quad * 8;
      Bh[jt] = *(const bf16x8f*)(const void*)(xchi + off);
      Bl[jt] = *(const bf16x8f*)(const void*)(xclo + off);
    }
#pragma unroll
    for (int it2 = 0; it2 < 2; it2++)
#pragma unroll
      for (int jt = 0; jt < 2; jt++) {
        acc[it2][jt] = __builtin_amdgcn_mfma_f32_16x16x32_bf16(Ah[it2], Bh[jt], acc[it2][jt], 0, 0, 0);
        acc[it2][jt] = __builtin_amdgcn_mfma_f32_16x16x32_bf16(Al[it2], Bh[jt], acc[it2][jt], 0, 0, 0);
        acc[it2][jt] = __builtin_amdgcn_mfma_f32_16x16x32_bf16(Ah[it2], Bl[jt], acc[it2][jt], 0, 0, 0);
      }
  }
  float* dst = eCp + ((size_t)kc * B_ + b) * C_ * C_;
#pragma unroll
  for (int it2 = 0; it2 < 2; it2++)
#pragma unroll
    for (int jt = 0; jt < 2; jt++) {
      int i = i0 + it2 * 16 + quad * 4;
      int j = j0 + jt * 16 + n16;
#pragma unroll
      for (int r = 0; r < 4; r++)
        dst[(size_t)(i + r) * C_ + j] = acc[it2][jt][r];
    }
}

// ---- k_cs v4: CAM softmax over -e; emit bf16 hi ONLY ----
__global__ __launch_bounds__(256) void k_cs(
    const float* __restrict__ eCp, bf16* __restrict__ ahi) {
  int row = blockIdx.x;
  int b = row >> 8, i = row & 255;
  int j = threadIdx.x;
  float e = 0.f;
#pragma unroll
  for (int kc = 0; kc < 8; kc++) e += eCp[(((size_t)kc * B_ + b) * C_ + i) * C_ + j];
  float ne = -e;
  __shared__ float buf[256];
  buf[j] = ne;
  __syncthreads();
  for (int st = 128; st >= 1; st >>= 1) {
    if (j < st) buf[j] = fmaxf(buf[j], buf[j + st]);
    __syncthreads();
  }
  float m = buf[0];
  __syncthreads();
  float p = __expf(ne - m);
  buf[j] = p;
  __syncthreads();
  for (int st = 128; st >= 1; st >>= 1) {
    if (j < st) buf[j] += buf[j + st];
    __syncthreads();
  }
  ahi[(size_t)row * C_ + j] = __float2bfloat16(p / buf[0]);
}

// ---- k_cam v5: hi-only (1 MFMA); fused out = gp*pamT + gc*cam + 2x ----
__global__ __launch_bounds__(512) void k_cam(
    const bf16* __restrict__ xthi,
    const bf16* __restrict__ ahi,
    const float* __restrict__ pamT, const float* __restrict__ x,
    const float* __restrict__ gpam, const float* __restrict__ gcam,
    float* __restrict__ out) {
  int b = blockIdx.y;
  int n0 = blockIdx.x * 32;
  int tid = threadIdx.x;
  int lane = tid & 63, wave = tid >> 6;
  int n16 = lane & 15, quad = lane >> 4;
  int c0 = wave * 32;

  f32x4 acc[2][2];                               // [nt][ct]
#pragma unroll
  for (int nt = 0; nt < 2; nt++)
#pragma unroll
    for (int ct = 0; ct < 2; ct++) acc[nt][ct] = (f32x4)(0.f);

#pragma unroll
  for (int kk = 0; kk < 8; kk++) {               // K = 256 = 8 x 32
    bf16x8f Ah[2], Bh[2];
#pragma unroll
    for (int nt = 0; nt < 2; nt++) {
      size_t off = ((size_t)b * N_ + n0 + nt * 16 + n16) * C_ + kk * 32 + quad * 8;
      Ah[nt] = *(const bf16x8f*)(const void*)(xthi + off);
    }
#pragma unroll
    for (int ct = 0; ct < 2; ct++) {
      size_t off = ((size_t)b * C_ + c0 + ct * 16 + n16) * C_ + kk * 32 + quad * 8;
      Bh[ct] = *(const bf16x8f*)(const void*)(ahi + off);
    }
#pragma unroll
    for (int nt = 0; nt < 2; nt++)
#pragma unroll
      for (int ct = 0; ct < 2; ct++)
        acc[nt][ct] = __builtin_amdgcn_mfma_f32_16x16x32_bf16(Ah[nt], Bh[ct], acc[nt][ct], 0, 0, 0);
  }
  float gp = gpam[0], gc = gcam[0];
#pragma unroll
  for (int nt = 0; nt < 2; nt++)
#pragma unroll
    for (int ct = 0; ct < 2; ct++) {
      int c = c0 + ct * 16 + n16;
      int nb = n0 + nt * 16 + quad * 4;
      const float* xp = x + ((size_t)b * C_ + c) * N_ + nb;
      float4 x4 = *(const float4*)(const void*)xp;
      float4 o4;
      o4.x = gp * pamT[((size_t)b * N_ + nb + 0) * C_ + c] + gc * acc[nt][ct][0] + 2.0f * x4.x;
      o4.y = gp * pamT[((size_t)b * N_ + nb + 1) * C_ + c] + gc * acc[nt][ct][1] + 2.0f * x4.y;
      o4.z = gp * pamT[((size_t)b * N_ + nb + 2) * C_ + c] + gc * acc[nt][ct][2] + 2.0f * x4.z;
      o4.w = gp * pamT[((size_t)b * N_ + nb + 3) * C_ + c] + gc * acc[nt][ct][3] + 2.0f * x4.w;
      *(float4*)(out + ((size_t)b * C_ + c) * N_ + nb) = o4;
    }
}

extern "C" void kernel_launch(void* const* d_in, const int* in_sizes, int n_in,
                              void* d_out, int out_size, void* d_ws, size_t ws_size,
                              hipStream_t stream) {
  const float* x  = (const float*)d_in[0];
  const float* wq = (const float*)d_in[1];
  const float* bq = (const float*)d_in[2];
  const float* wk = (const float*)d_in[3];
  const float* bk = (const float*)d_in[4];
  const float* wv = (const float*)d_in[5];
  const float* bv = (const float*)d_in[6];
  const float* gp = (const float*)d_in[7];
  const float* gc = (const float*)d_in[8];
  float* out = (float*)d_out;

  float* ws = (float*)d_ws;
  size_t o = 0;
  float* pamT  = ws + o; o += (size_t)B_ * N_ * C_;     // 2097152
  float* mp    = ws + o; o += (size_t)2 * B_ * N_;      // 16384 (unused, layout kept)
  float* lp    = ws + o; o += (size_t)2 * B_ * N_;      // 16384 (unused, layout kept)
  float* eCp   = ws + o; o += (size_t)8 * B_ * C_ * C_; // 1048576
  bf16*  ahi   = (bf16*)(ws + o); o += (size_t)B_ * C_ * C_ / 2;   // 65536 fl
  bf16*  alo   = (bf16*)(ws + o); o += (size_t)B_ * C_ * C_ / 2;   // 65536 fl (unused)
  bf16*  vbf   = (bf16*)(ws + o); o += (size_t)B_ * N_ * C_ / 2;   // 1048576
  bf16*  qhi   = (bf16*)(ws + o); o += (size_t)B_ * N_ * QK_ / 2;  // 131072
  bf16*  qlo   = (bf16*)(ws + o); o += (size_t)B_ * N_ * QK_ / 2;  // 131072
  bf16*  khi   = (bf16*)(ws + o); o += (size_t)B_ * N_ * QK_ / 2;  // 131072
  bf16*  klo   = (bf16*)(ws + o); o += (size_t)B_ * N_ * QK_ / 2;  // 131072
  float* xtbuf = ws + o; o += (size_t)2 * B_ * N_ * QK_ * 4;       // 2097152 (xT hi/lo)
  bf16* xthi = (bf16*)xtbuf;
  bf16* xtlo = (bf16*)(xtbuf + (size_t)B_ * N_ * C_ / 2);
  // weight hi/lo buffers alias eCp (dead until k_ce2; k_qkp/k_vbf2 run first)
  bf16* wqkh = (bf16*)eCp;
  bf16* wqkl = wqkh + (size_t)64 * C_;
  bf16* wvh  = wqkl + (size_t)64 * C_;
  bf16* wvl  = wvh + (size_t)C_ * C_;
  // x [b][c][n] hi/lo alias pamT (dead until k_pbm; k_ce2/k_cs run before)
  bf16* xchi = (bf16*)pamT;
  bf16* xclo = xchi + (size_t)B_ * C_ * N_;     // 2x 1M floats = exact fit
  (void)mp; (void)lp; (void)alo;
  // total ~6.8 M floats = 27.4 MB (unchanged)

  k_wcv<<<dim3((64 * C_ + C_ * C_) / 256), dim3(256), 0, stream>>>(wq, wk, wv, wqkh, wqkl, wvh, wvl);
  k_xt<<<dim3(N_ / 64, C_ / 64, B_), dim3(256), 0, stream>>>(x, xthi, xtlo, xchi, xclo);
  k_qkp<<<dim3(N_ / 32, B_), dim3(256), 0, stream>>>(xthi, xtlo, wqkh, wqkl, bq, bk, qhi, qlo, khi, klo);
  k_vbf2<<<dim3(N_ / 32, B_), dim3(256), 0, stream>>>(xthi, xtlo, wvh, wvl, bv, vbf);
  k_ce2<<<dim3(16, 8, B_), dim3(256), 0, stream>>>(xchi, xclo, eCp);
  k_cs<<<dim3(B_ * C_), dim3(256), 0, stream>>>(eCp, ahi);
  k_pbm<<<dim3(N_ / 64, 2, B_), dim3(512), 0, stream>>>(qhi, qlo, khi, klo, vbf, pamT);
  k_cam<<<dim3(N_ / 32, B_), dim3(512), 0, stream>>>(xthi, ahi, pamT, x, gp, gc, out);
}